// Round 1
// baseline (1434.249 us; speedup 1.0000x reference)
//
#include <hip/hip_runtime.h>
#include <cstddef>
#include <cstdint>

// ---------------------------------------------------------------------------
// GAT encoder: 3x (GEMM -> attention logits -> segment-softmax aggregate) + proj
// All fp32. CSR built per call from edge_index (+self loops).
// ---------------------------------------------------------------------------

// Detect whether edge_index is stored as int32 or int64 on device.
// If int64 (little-endian), every odd int32 word is a high word == 0
// (node ids < 50000). If int32, odd words are random node ids.
__global__ __launch_bounds__(64) void detect_i64_kernel(const int* __restrict__ ei,
                                                        int* __restrict__ flag) {
  if (threadIdx.x == 0) {
    int is32 = 0;
    for (int i = 1; i < 1001; i += 2) {
      if (ei[i] != 0) { is32 = 1; break; }
    }
    *flag = is32;  // 1 => int32 layout, 0 => int64 layout
  }
}

__device__ __forceinline__ int load_src(const int* ei, int is32, int E, int e) {
  return is32 ? ei[e] : ei[2 * e];
}
__device__ __forceinline__ int load_dst(const int* ei, int is32, int E, int e) {
  return is32 ? ei[E + e] : ei[2 * (E + e)];
}

__global__ __launch_bounds__(256) void deg_kernel(const int* __restrict__ ei,
                                                  const int* __restrict__ flag,
                                                  int E, int N, int* __restrict__ deg) {
  int e = blockIdx.x * 256 + threadIdx.x;
  if (e >= E + N) return;
  int d = (e < E) ? load_dst(ei, *flag, E, e) : (e - E);
  atomicAdd(&deg[d], 1);
}

// Single-block inclusive scan -> rowptr[0..N], N up to ~64k handled in chunks.
__global__ __launch_bounds__(1024) void scan_kernel(const int* __restrict__ deg,
                                                    int* __restrict__ rowptr, int N) {
  __shared__ int buf[1024];
  __shared__ int carry;
  int t = threadIdx.x;
  if (t == 0) { carry = 0; rowptr[0] = 0; }
  __syncthreads();
  for (int base = 0; base < N; base += 1024) {
    int i = base + t;
    int v = (i < N) ? deg[i] : 0;
    buf[t] = v;
    __syncthreads();
    for (int off = 1; off < 1024; off <<= 1) {
      int add = (t >= off) ? buf[t - off] : 0;
      __syncthreads();
      buf[t] += add;
      __syncthreads();
    }
    if (i < N) rowptr[i + 1] = carry + buf[t];
    __syncthreads();
    if (t == 0) carry += buf[1023];
    __syncthreads();
  }
}

__global__ __launch_bounds__(256) void fill_kernel(const int* __restrict__ ei,
                                                   const int* __restrict__ flag,
                                                   int E, int N,
                                                   const int* __restrict__ rowptr,
                                                   int* __restrict__ fillc,
                                                   int* __restrict__ colbuf) {
  int e = blockIdx.x * 256 + threadIdx.x;
  if (e >= E + N) return;
  int s, d;
  if (e < E) { int is32 = *flag; s = load_src(ei, is32, E, e); d = load_dst(ei, is32, E, e); }
  else { s = e - E; d = s; }
  int pos = atomicAdd(&fillc[d], 1);
  colbuf[rowptr[d] + pos] = s;
}

// Ws[f*4+h] = sum_d W[f, h*128+d] * a_src[h, d]   (and same for Wd/a_dst)
__global__ __launch_bounds__(512) void wsd_kernel(const float* __restrict__ W,
                                                  const float* __restrict__ a_src,
                                                  const float* __restrict__ a_dst,
                                                  float* __restrict__ Ws,
                                                  float* __restrict__ Wd) {
  int f = threadIdx.x >> 2;
  int h = threadIdx.x & 3;
  float s = 0.f, d = 0.f;
  for (int dd = 0; dd < 128; ++dd) {
    float w = W[f * 512 + h * 128 + dd];
    s += w * a_src[h * 128 + dd];
    d += w * a_dst[h * 128 + dd];
  }
  Ws[f * 4 + h] = s;
  Wd[f * 4 + h] = d;
}

// C[M,N] = A[M,K] @ B[K,N] (+bias). 64x64 tiles, 256 threads, 4x4 microtile.
__global__ __launch_bounds__(256) void gemm_kernel(const float* __restrict__ A,
                                                   const float* __restrict__ B,
                                                   float* __restrict__ C,
                                                   int M, int N, int K,
                                                   const float* __restrict__ bias) {
  __shared__ float As[64][33];
  __shared__ float Bs[32][65];
  int tid = threadIdx.x;
  int tx = tid & 15, ty = tid >> 4;
  int row0 = blockIdx.y * 64, col0 = blockIdx.x * 64;
  float acc[4][4] = {};
  for (int kt = 0; kt < K; kt += 32) {
    #pragma unroll
    for (int i = 0; i < 8; ++i) {
      int idx = tid + i * 256;
      int r = idx >> 5, c = idx & 31;
      int gr = row0 + r;
      As[r][c] = (gr < M) ? A[(size_t)gr * K + kt + c] : 0.f;
    }
    #pragma unroll
    for (int i = 0; i < 8; ++i) {
      int idx = tid + i * 256;
      int r = idx >> 6, c = idx & 63;
      Bs[r][c] = B[(size_t)(kt + r) * N + col0 + c];
    }
    __syncthreads();
    #pragma unroll
    for (int k = 0; k < 32; ++k) {
      float a[4], b[4];
      #pragma unroll
      for (int i = 0; i < 4; ++i) a[i] = As[ty * 4 + i][k];
      #pragma unroll
      for (int j = 0; j < 4; ++j) b[j] = Bs[k][tx * 4 + j];
      #pragma unroll
      for (int i = 0; i < 4; ++i)
        #pragma unroll
        for (int j = 0; j < 4; ++j) acc[i][j] += a[i] * b[j];
    }
    __syncthreads();
  }
  float bv[4];
  #pragma unroll
  for (int j = 0; j < 4; ++j) bv[j] = bias ? bias[col0 + tx * 4 + j] : 0.f;
  #pragma unroll
  for (int i = 0; i < 4; ++i) {
    int r = row0 + ty * 4 + i;
    if (r < M) {
      #pragma unroll
      for (int j = 0; j < 4; ++j)
        C[(size_t)r * N + col0 + tx * 4 + j] = acc[i][j] + bv[j];
    }
  }
}

// al_src/al_dst [N,4] = h @ Ws / h @ Wd. One wave per node.
__global__ __launch_bounds__(256) void al_kernel(const float* __restrict__ h,
                                                 const float* __restrict__ Ws,
                                                 const float* __restrict__ Wd,
                                                 float* __restrict__ al_src,
                                                 float* __restrict__ al_dst, int N) {
  __shared__ float sWs[512], sWd[512];
  int t = threadIdx.x;
  sWs[t] = Ws[t]; sWs[t + 256] = Ws[t + 256];
  sWd[t] = Wd[t]; sWd[t + 256] = Wd[t + 256];
  __syncthreads();
  int wave = t >> 6, lane = t & 63;
  int n = blockIdx.x * 4 + wave;
  if (n >= N) return;
  float2 hv = *(const float2*)&h[(size_t)n * 128 + lane * 2];
  float p[8];
  #pragma unroll
  for (int hh = 0; hh < 4; ++hh) {
    p[hh]     = hv.x * sWs[(2 * lane) * 4 + hh] + hv.y * sWs[(2 * lane + 1) * 4 + hh];
    p[4 + hh] = hv.x * sWd[(2 * lane) * 4 + hh] + hv.y * sWd[(2 * lane + 1) * 4 + hh];
  }
  #pragma unroll
  for (int off = 32; off; off >>= 1)
    #pragma unroll
    for (int i = 0; i < 8; ++i) p[i] += __shfl_xor(p[i], off);
  if (lane == 0) {
    #pragma unroll
    for (int hh = 0; hh < 4; ++hh) {
      al_src[n * 4 + hh] = p[hh];
      al_dst[n * 4 + hh] = p[4 + hh];
    }
  }
}

// One block (256 thr) per destination node. Wave h handles head h.
// Pass 1: max logit. Pass 2: exp-weighted accumulate of xh[src].
// Epilogue: mean over heads + bias + relu.
__global__ __launch_bounds__(256) void agg_kernel(const float* __restrict__ xh,
                                                  const float* __restrict__ al_src,
                                                  const float* __restrict__ al_dst,
                                                  const int* __restrict__ rowptr,
                                                  const int* __restrict__ colbuf,
                                                  const float* __restrict__ bias,
                                                  float* __restrict__ hout, int N) {
  int n = blockIdx.x;
  int h = threadIdx.x >> 6;
  int lane = threadIdx.x & 63;
  int beg = rowptr[n], end = rowptr[n + 1];
  float ald = al_dst[n * 4 + h];
  float m = -1e30f;
  for (int j = beg; j < end; ++j) {
    int s = colbuf[j];
    float e = al_src[s * 4 + h] + ald;
    e = (e > 0.f) ? e : 0.2f * e;
    m = fmaxf(m, e);
  }
  float accx = 0.f, accy = 0.f, ssum = 0.f;
  for (int j = beg; j < end; ++j) {
    int s = colbuf[j];
    float e = al_src[s * 4 + h] + ald;
    e = (e > 0.f) ? e : 0.2f * e;
    float w = expf(e - m);
    ssum += w;
    float2 xv = *(const float2*)&xh[(size_t)(s * 4 + h) * 128 + lane * 2];
    accx += w * xv.x;
    accy += w * xv.y;
  }
  float inv = 1.f / (ssum + 1e-16f);
  __shared__ float red[4][128];
  red[h][lane * 2] = accx * inv;
  red[h][lane * 2 + 1] = accy * inv;
  __syncthreads();
  if (threadIdx.x < 128) {
    int d = threadIdx.x;
    float v = 0.25f * (red[0][d] + red[1][d] + red[2][d] + red[3][d]) + bias[d];
    hout[(size_t)n * 128 + d] = fmaxf(v, 0.f);
  }
}

extern "C" void kernel_launch(void* const* d_in, const int* in_sizes, int n_in,
                              void* d_out, int out_size, void* d_ws, size_t ws_size,
                              hipStream_t stream) {
  const float* x  = (const float*)d_in[0];
  const int*   ei = (const int*)d_in[1];
  const float* Wl[3]  = {(const float*)d_in[2], (const float*)d_in[6], (const float*)d_in[10]};
  const float* asr[3] = {(const float*)d_in[3], (const float*)d_in[7], (const float*)d_in[11]};
  const float* adr[3] = {(const float*)d_in[4], (const float*)d_in[8], (const float*)d_in[12]};
  const float* bl[3]  = {(const float*)d_in[5], (const float*)d_in[9], (const float*)d_in[13]};
  const float* Wp = (const float*)d_in[14];
  const float* bp = (const float*)d_in[15];

  const int N = in_sizes[0] / 128;   // 50000
  const int E = in_sizes[1] / 2;     // 400000
  const int EN = E + N;

  // workspace carve
  char* ws = (char*)d_ws;
  size_t off = 0;
  auto carve = [&](size_t bytes) -> void* {
    void* p = ws + off;
    off = (off + bytes + 255) & ~(size_t)255;
    return p;
  };
  float* xh     = (float*)carve((size_t)N * 512 * 4);  // 102.4 MB
  float* h0     = (float*)carve((size_t)N * 128 * 4);  // 25.6 MB
  float* alsrc  = (float*)carve((size_t)N * 4 * 4);
  float* aldst  = (float*)carve((size_t)N * 4 * 4);
  float* Wsb    = (float*)carve(512 * 4);
  float* Wdb    = (float*)carve(512 * 4);
  int*   rowptr = (int*)carve((size_t)(N + 1) * 4);
  int*   deg    = (int*)carve((size_t)N * 4);
  int*   fillc  = (int*)carve((size_t)N * 4);
  int*   colbuf = (int*)carve((size_t)EN * 4);
  int*   flag   = (int*)carve(256);
  float* h1 = (float*)d_out;  // reuse d_out as the second ping-pong buffer

  // ---- CSR build (once, serves all 3 layers) ----
  detect_i64_kernel<<<1, 64, 0, stream>>>(ei, flag);
  hipMemsetAsync(deg, 0, (size_t)N * 4, stream);
  hipMemsetAsync(fillc, 0, (size_t)N * 4, stream);
  int ebl = (EN + 255) / 256;
  deg_kernel<<<ebl, 256, 0, stream>>>(ei, flag, E, N, deg);
  scan_kernel<<<1, 1024, 0, stream>>>(deg, rowptr, N);
  fill_kernel<<<ebl, 256, 0, stream>>>(ei, flag, E, N, rowptr, fillc, colbuf);

  // ---- 3 GAT layers ----
  const float* hin = x;
  float* houts[3] = {h0, h1, h0};
  int mtiles = (N + 63) / 64;
  for (int L = 0; L < 3; ++L) {
    wsd_kernel<<<1, 512, 0, stream>>>(Wl[L], asr[L], adr[L], Wsb, Wdb);
    gemm_kernel<<<dim3(8, mtiles), 256, 0, stream>>>(hin, Wl[L], xh, N, 512, 128, nullptr);
    al_kernel<<<(N + 3) / 4, 256, 0, stream>>>(hin, Wsb, Wdb, alsrc, aldst, N);
    agg_kernel<<<N, 256, 0, stream>>>(xh, alsrc, aldst, rowptr, colbuf, bl[L], houts[L], N);
    hin = houts[L];
  }

  // ---- final projection: out = h @ Wp + bp ----
  gemm_kernel<<<dim3(2, mtiles), 256, 0, stream>>>(hin, Wp, (float*)d_out, N, 128, 128, bp);
}

// Round 2
// 1151.893 us; speedup vs baseline: 1.2451x; 1.2451x over previous
//
#include <hip/hip_runtime.h>
#include <cstddef>
#include <cstdint>

typedef short short8 __attribute__((ext_vector_type(8)));
typedef float f32x4 __attribute__((ext_vector_type(4)));
typedef unsigned short ushort_t;
typedef ushort_t ushort4v __attribute__((ext_vector_type(4)));
typedef float f32x4v __attribute__((ext_vector_type(4)));

__device__ __forceinline__ float bf16_to_f(ushort_t u) {
  union { unsigned int i; float f; } v; v.i = ((unsigned int)u) << 16; return v.f;
}
__device__ __forceinline__ ushort_t f_to_bf16(float f) {
  union { float ff; unsigned int i; } v; v.ff = f;
  unsigned int x = v.i;
  unsigned int lsb = (x >> 16) & 1u;
  x += 0x7fffu + lsb;               // round-to-nearest-even
  return (ushort_t)(x >> 16);
}

__device__ __forceinline__ void gload_lds16(const void* g, void* l) {
  __builtin_amdgcn_global_load_lds((const __attribute__((address_space(1))) void*)g,
                                   (__attribute__((address_space(3))) void*)l, 16, 0, 0);
}

// ---------------------------------------------------------------------------
// CSR build (unchanged from round 0)
// ---------------------------------------------------------------------------
__global__ __launch_bounds__(64) void detect_i64_kernel(const int* __restrict__ ei,
                                                        int* __restrict__ flag) {
  if (threadIdx.x == 0) {
    int is32 = 0;
    for (int i = 1; i < 1001; i += 2) {
      if (ei[i] != 0) { is32 = 1; break; }
    }
    *flag = is32;
  }
}

__device__ __forceinline__ int load_src(const int* ei, int is32, int E, int e) {
  return is32 ? ei[e] : ei[2 * e];
}
__device__ __forceinline__ int load_dst(const int* ei, int is32, int E, int e) {
  return is32 ? ei[E + e] : ei[2 * (E + e)];
}

__global__ __launch_bounds__(256) void deg_kernel(const int* __restrict__ ei,
                                                  const int* __restrict__ flag,
                                                  int E, int N, int* __restrict__ deg) {
  int e = blockIdx.x * 256 + threadIdx.x;
  if (e >= E + N) return;
  int d = (e < E) ? load_dst(ei, *flag, E, e) : (e - E);
  atomicAdd(&deg[d], 1);
}

__global__ __launch_bounds__(1024) void scan_kernel(const int* __restrict__ deg,
                                                    int* __restrict__ rowptr, int N) {
  __shared__ int buf[1024];
  __shared__ int carry;
  int t = threadIdx.x;
  if (t == 0) { carry = 0; rowptr[0] = 0; }
  __syncthreads();
  for (int base = 0; base < N; base += 1024) {
    int i = base + t;
    int v = (i < N) ? deg[i] : 0;
    buf[t] = v;
    __syncthreads();
    for (int off = 1; off < 1024; off <<= 1) {
      int add = (t >= off) ? buf[t - off] : 0;
      __syncthreads();
      buf[t] += add;
      __syncthreads();
    }
    if (i < N) rowptr[i + 1] = carry + buf[t];
    __syncthreads();
    if (t == 0) carry += buf[1023];
    __syncthreads();
  }
}

__global__ __launch_bounds__(256) void fill_kernel(const int* __restrict__ ei,
                                                   const int* __restrict__ flag,
                                                   int E, int N,
                                                   const int* __restrict__ rowptr,
                                                   int* __restrict__ fillc,
                                                   int* __restrict__ colbuf) {
  int e = blockIdx.x * 256 + threadIdx.x;
  if (e >= E + N) return;
  int s, d;
  if (e < E) { int is32 = *flag; s = load_src(ei, is32, E, e); d = load_dst(ei, is32, E, e); }
  else { s = e - E; d = s; }
  int pos = atomicAdd(&fillc[d], 1);
  colbuf[rowptr[d] + pos] = s;
}

// ---------------------------------------------------------------------------
// split / transpose prep for MFMA GEMM
// ---------------------------------------------------------------------------
// h [n_real floats, padded to n_total] -> hi/lo bf16 arrays (zero padded)
__global__ __launch_bounds__(256) void split_h_kernel(const float* __restrict__ h,
                                                      ushort_t* __restrict__ hi,
                                                      ushort_t* __restrict__ lo,
                                                      int n_real, int n_total) {
  int i = (blockIdx.x * 256 + threadIdx.x) * 4;
  if (i >= n_total) return;
  f32x4v v = (i < n_real) ? *(const f32x4v*)&h[i] : f32x4v{0.f, 0.f, 0.f, 0.f};
  ushort4v h4, l4;
#pragma unroll
  for (int k = 0; k < 4; ++k) {
    float f = v[k];
    ushort_t hb = f_to_bf16(f);
    float res = f - bf16_to_f(hb);
    h4[k] = hb;
    l4[k] = f_to_bf16(res);
  }
  *(ushort4v*)&hi[i] = h4;
  *(ushort4v*)&lo[i] = l4;
}

// W [K=128][Nn] fp32 -> Wt_hi/Wt_lo [Nn][128] bf16
__global__ __launch_bounds__(256) void split_wt_kernel(const float* __restrict__ W,
                                                       ushort_t* __restrict__ hi,
                                                       ushort_t* __restrict__ lo,
                                                       int Nn) {
  int t = blockIdx.x * 256 + threadIdx.x;
  if (t >= 128 * Nn) return;
  int n = t >> 7, k = t & 127;
  float f = W[(size_t)k * Nn + n];
  ushort_t hb = f_to_bf16(f);
  hi[t] = hb;
  lo[t] = f_to_bf16(f - bf16_to_f(hb));
}

// ---------------------------------------------------------------------------
// MFMA GEMM: C[M, Nn] = A[M,128] @ B[128,Nn]  (split-bf16 3-pass, fp32-grade)
// A given as Ahi/Alo [Mp][128] bf16, B as Bthi/Btlo [Nn][128] bf16 (transposed).
// 128x128 tile per block, 4 waves in 2x2, 4x4 frags of 16x16x32.
// ---------------------------------------------------------------------------
__global__ __launch_bounds__(256) void mfma_gemm_kernel(
    const ushort_t* __restrict__ Ahi, const ushort_t* __restrict__ Alo,
    const ushort_t* __restrict__ Bthi, const ushort_t* __restrict__ Btlo,
    float* __restrict__ C, int M, int ldc, const float* __restrict__ bias, int guard) {
  __shared__ ushort_t As[2][128 * 128];  // 64 KB, slot-swizzled rows of 256 B
  int tid = threadIdx.x;
  int wave = tid >> 6, lane = tid & 63;
  int wr = wave >> 1, wc = wave & 1;
  int row0 = blockIdx.x * 128, col0 = blockIdx.y * 128;

  // ---- stage A tile (hi+lo) into LDS: linear dest, source-side XOR swizzle ----
#pragma unroll
  for (int p = 0; p < 2; ++p) {
    const ushort_t* src = p ? Alo : Ahi;
#pragma unroll
    for (int it = 0; it < 8; ++it) {
      int chunk = wave + it * 4;            // wave-uniform
      int row = chunk * 4 + (lane >> 4);    // 0..127
      int sp = lane & 15;                   // physical 16B slot within 256B row
      int sl = sp ^ (row & 7);              // logical slot stored here
      gload_lds16(src + (size_t)(row0 + row) * 128 + sl * 8,
                  &As[p][chunk * 512]);
    }
  }
  __syncthreads();

  f32x4 acc[4][4] = {};
  int krow = lane >> 4;   // 0..3
  int ml = lane & 15;

#pragma unroll
  for (int kt = 0; kt < 4; ++kt) {
    short8 ah[4], al_[4], bh[4], bl[4];
    int sl = kt * 4 + krow;                 // logical slot for this frag
#pragma unroll
    for (int f = 0; f < 4; ++f) {
      int row = wr * 64 + f * 16 + ml;
      int phys = sl ^ (row & 7);
      int off = row * 128 + phys * 8;
      ah[f]  = *(const short8*)&As[0][off];
      al_[f] = *(const short8*)&As[1][off];
    }
    int k0 = kt * 32 + krow * 8;
#pragma unroll
    for (int f = 0; f < 4; ++f) {
      int n = col0 + wc * 64 + f * 16 + ml;
      bh[f] = *(const short8*)&Bthi[(size_t)n * 128 + k0];
      bl[f] = *(const short8*)&Btlo[(size_t)n * 128 + k0];
    }
#pragma unroll
    for (int i = 0; i < 4; ++i)
#pragma unroll
      for (int j = 0; j < 4; ++j) {
        acc[i][j] = __builtin_amdgcn_mfma_f32_16x16x32_bf16(ah[i],  bh[j], acc[i][j], 0, 0, 0);
        acc[i][j] = __builtin_amdgcn_mfma_f32_16x16x32_bf16(ah[i],  bl[j], acc[i][j], 0, 0, 0);
        acc[i][j] = __builtin_amdgcn_mfma_f32_16x16x32_bf16(al_[i], bh[j], acc[i][j], 0, 0, 0);
      }
  }

  // ---- epilogue: C/D layout col=lane&15, row=(lane>>4)*4+reg ----
#pragma unroll
  for (int j = 0; j < 4; ++j) {
    int col = col0 + wc * 64 + j * 16 + ml;
    float bv = bias ? bias[col] : 0.f;
#pragma unroll
    for (int i = 0; i < 4; ++i) {
#pragma unroll
      for (int r = 0; r < 4; ++r) {
        int row = row0 + wr * 64 + i * 16 + krow * 4 + r;
        if (!guard || row < M) C[(size_t)row * ldc + col] = acc[i][j][r] + bv;
      }
    }
  }
}

// ---------------------------------------------------------------------------
// attention-logit folding + per-node logits (unchanged)
// ---------------------------------------------------------------------------
__global__ __launch_bounds__(512) void wsd_kernel(const float* __restrict__ W,
                                                  const float* __restrict__ a_src,
                                                  const float* __restrict__ a_dst,
                                                  float* __restrict__ Ws,
                                                  float* __restrict__ Wd) {
  int f = threadIdx.x >> 2;
  int h = threadIdx.x & 3;
  float s = 0.f, d = 0.f;
  for (int dd = 0; dd < 128; ++dd) {
    float w = W[f * 512 + h * 128 + dd];
    s += w * a_src[h * 128 + dd];
    d += w * a_dst[h * 128 + dd];
  }
  Ws[f * 4 + h] = s;
  Wd[f * 4 + h] = d;
}

__global__ __launch_bounds__(256) void al_kernel(const float* __restrict__ h,
                                                 const float* __restrict__ Ws,
                                                 const float* __restrict__ Wd,
                                                 float* __restrict__ al_src,
                                                 float* __restrict__ al_dst, int N) {
  __shared__ float sWs[512], sWd[512];
  int t = threadIdx.x;
  sWs[t] = Ws[t]; sWs[t + 256] = Ws[t + 256];
  sWd[t] = Wd[t]; sWd[t + 256] = Wd[t + 256];
  __syncthreads();
  int wave = t >> 6, lane = t & 63;
  int n = blockIdx.x * 4 + wave;
  if (n >= N) return;
  float2 hv = *(const float2*)&h[(size_t)n * 128 + lane * 2];
  float p[8];
#pragma unroll
  for (int hh = 0; hh < 4; ++hh) {
    p[hh]     = hv.x * sWs[(2 * lane) * 4 + hh] + hv.y * sWs[(2 * lane + 1) * 4 + hh];
    p[4 + hh] = hv.x * sWd[(2 * lane) * 4 + hh] + hv.y * sWd[(2 * lane + 1) * 4 + hh];
  }
#pragma unroll
  for (int off = 32; off; off >>= 1)
#pragma unroll
    for (int i = 0; i < 8; ++i) p[i] += __shfl_xor(p[i], off);
  if (lane == 0) {
#pragma unroll
    for (int hh = 0; hh < 4; ++hh) {
      al_src[n * 4 + hh] = p[hh];
      al_dst[n * 4 + hh] = p[4 + hh];
    }
  }
}

// ---------------------------------------------------------------------------
// segment-softmax aggregation (unchanged)
// ---------------------------------------------------------------------------
__global__ __launch_bounds__(256) void agg_kernel(const float* __restrict__ xh,
                                                  const float* __restrict__ al_src,
                                                  const float* __restrict__ al_dst,
                                                  const int* __restrict__ rowptr,
                                                  const int* __restrict__ colbuf,
                                                  const float* __restrict__ bias,
                                                  float* __restrict__ hout, int N) {
  int n = blockIdx.x;
  int h = threadIdx.x >> 6;
  int lane = threadIdx.x & 63;
  int beg = rowptr[n], end = rowptr[n + 1];
  float ald = al_dst[n * 4 + h];
  float m = -1e30f;
  for (int j = beg; j < end; ++j) {
    int s = colbuf[j];
    float e = al_src[s * 4 + h] + ald;
    e = (e > 0.f) ? e : 0.2f * e;
    m = fmaxf(m, e);
  }
  float accx = 0.f, accy = 0.f, ssum = 0.f;
  for (int j = beg; j < end; ++j) {
    int s = colbuf[j];
    float e = al_src[s * 4 + h] + ald;
    e = (e > 0.f) ? e : 0.2f * e;
    float w = expf(e - m);
    ssum += w;
    float2 xv = *(const float2*)&xh[(size_t)(s * 4 + h) * 128 + lane * 2];
    accx += w * xv.x;
    accy += w * xv.y;
  }
  float inv = 1.f / (ssum + 1e-16f);
  __shared__ float red[4][128];
  red[h][lane * 2] = accx * inv;
  red[h][lane * 2 + 1] = accy * inv;
  __syncthreads();
  if (threadIdx.x < 128) {
    int d = threadIdx.x;
    float v = 0.25f * (red[0][d] + red[1][d] + red[2][d] + red[3][d]) + bias[d];
    hout[(size_t)n * 128 + d] = fmaxf(v, 0.f);
  }
}

// ---------------------------------------------------------------------------
extern "C" void kernel_launch(void* const* d_in, const int* in_sizes, int n_in,
                              void* d_out, int out_size, void* d_ws, size_t ws_size,
                              hipStream_t stream) {
  const float* x  = (const float*)d_in[0];
  const int*   ei = (const int*)d_in[1];
  const float* Wl[3]  = {(const float*)d_in[2], (const float*)d_in[6], (const float*)d_in[10]};
  const float* asr[3] = {(const float*)d_in[3], (const float*)d_in[7], (const float*)d_in[11]};
  const float* adr[3] = {(const float*)d_in[4], (const float*)d_in[8], (const float*)d_in[12]};
  const float* bl[3]  = {(const float*)d_in[5], (const float*)d_in[9], (const float*)d_in[13]};
  const float* Wp = (const float*)d_in[14];
  const float* bp = (const float*)d_in[15];

  const int N = in_sizes[0] / 128;   // 50000
  const int E = in_sizes[1] / 2;     // 400000
  const int EN = E + N;
  const int Mtiles = (N + 127) / 128;  // 391
  const int Mp = Mtiles * 128;         // 50048

  char* ws = (char*)d_ws;
  size_t off = 0;
  auto carve = [&](size_t bytes) -> void* {
    void* p = ws + off;
    off = (off + bytes + 255) & ~(size_t)255;
    return p;
  };
  float*    xh     = (float*)carve((size_t)Mp * 512 * 4);   // 102.5 MB (padded rows)
  float*    h0     = (float*)carve((size_t)N * 128 * 4);    // 25.6 MB
  ushort_t* hhi    = (ushort_t*)carve((size_t)Mp * 128 * 2);
  ushort_t* hlo    = (ushort_t*)carve((size_t)Mp * 128 * 2);
  ushort_t* wthi   = (ushort_t*)carve((size_t)512 * 128 * 2);
  ushort_t* wtlo   = (ushort_t*)carve((size_t)512 * 128 * 2);
  float*    alsrc  = (float*)carve((size_t)N * 4 * 4);
  float*    aldst  = (float*)carve((size_t)N * 4 * 4);
  float*    Wsb    = (float*)carve(512 * 4);
  float*    Wdb    = (float*)carve(512 * 4);
  int*      rowptr = (int*)carve((size_t)(N + 1) * 4);
  int*      deg    = (int*)carve((size_t)N * 4);
  int*      fillc  = (int*)carve((size_t)N * 4);
  int*      colbuf = (int*)carve((size_t)EN * 4);
  int*      flag   = (int*)carve(256);
  float*    h1 = (float*)d_out;  // second ping-pong buffer

  // ---- CSR build ----
  detect_i64_kernel<<<1, 64, 0, stream>>>(ei, flag);
  hipMemsetAsync(deg, 0, (size_t)N * 4, stream);
  hipMemsetAsync(fillc, 0, (size_t)N * 4, stream);
  int ebl = (EN + 255) / 256;
  deg_kernel<<<ebl, 256, 0, stream>>>(ei, flag, E, N, deg);
  scan_kernel<<<1, 1024, 0, stream>>>(deg, rowptr, N);
  fill_kernel<<<ebl, 256, 0, stream>>>(ei, flag, E, N, rowptr, fillc, colbuf);

  const int n_real = N * 128, n_total = Mp * 128;
  int splh_bl = (n_total / 4 + 255) / 256;

  // ---- 3 GAT layers ----
  const float* hin = x;
  float* houts[3] = {h0, h1, h0};
  for (int L = 0; L < 3; ++L) {
    split_h_kernel<<<splh_bl, 256, 0, stream>>>(hin, hhi, hlo, n_real, n_total);
    split_wt_kernel<<<(512 * 128) / 256, 256, 0, stream>>>(Wl[L], wthi, wtlo, 512);
    wsd_kernel<<<1, 512, 0, stream>>>(Wl[L], asr[L], adr[L], Wsb, Wdb);
    mfma_gemm_kernel<<<dim3(Mtiles, 4), 256, 0, stream>>>(hhi, hlo, wthi, wtlo,
                                                          xh, N, 512, nullptr, 0);
    al_kernel<<<(N + 3) / 4, 256, 0, stream>>>(hin, Wsb, Wdb, alsrc, aldst, N);
    agg_kernel<<<N, 256, 0, stream>>>(xh, alsrc, aldst, rowptr, colbuf, bl[L], houts[L], N);
    hin = houts[L];
  }

  // ---- final projection: out = h @ Wp + bp ----
  split_h_kernel<<<splh_bl, 256, 0, stream>>>(hin, hhi, hlo, n_real, n_total);
  split_wt_kernel<<<(128 * 128) / 256, 256, 0, stream>>>(Wp, wthi, wtlo, 128);
  mfma_gemm_kernel<<<dim3(Mtiles, 1), 256, 0, stream>>>(hhi, hlo, wthi, wtlo,
                                                        (float*)d_out, N, 128, bp, 1);
}

// Round 3
// 833.587 us; speedup vs baseline: 1.7206x; 1.3819x over previous
//
#include <hip/hip_runtime.h>
#include <cstddef>
#include <cstdint>

typedef short short8 __attribute__((ext_vector_type(8)));
typedef float f32x4 __attribute__((ext_vector_type(4)));
typedef unsigned short ushort_t;
typedef ushort_t ushort4v __attribute__((ext_vector_type(4)));
typedef float f32x4v __attribute__((ext_vector_type(4)));

__device__ __forceinline__ float bf16_to_f(ushort_t u) {
  union { unsigned int i; float f; } v; v.i = ((unsigned int)u) << 16; return v.f;
}
__device__ __forceinline__ ushort_t f_to_bf16(float f) {
  union { float ff; unsigned int i; } v; v.ff = f;
  unsigned int x = v.i;
  unsigned int lsb = (x >> 16) & 1u;
  x += 0x7fffu + lsb;               // round-to-nearest-even
  return (ushort_t)(x >> 16);
}

__device__ __forceinline__ void gload_lds16(const void* g, void* l) {
  __builtin_amdgcn_global_load_lds((const __attribute__((address_space(1))) void*)g,
                                   (__attribute__((address_space(3))) void*)l, 16, 0, 0);
}

// ---------------------------------------------------------------------------
// CSR build
// ---------------------------------------------------------------------------
__global__ __launch_bounds__(64) void detect_i64_kernel(const int* __restrict__ ei,
                                                        int* __restrict__ flag) {
  if (threadIdx.x == 0) {
    int is32 = 0;
    for (int i = 1; i < 1001; i += 2) {
      if (ei[i] != 0) { is32 = 1; break; }
    }
    *flag = is32;
  }
}

__device__ __forceinline__ int load_src(const int* ei, int is32, int E, int e) {
  return is32 ? ei[e] : ei[2 * e];
}
__device__ __forceinline__ int load_dst(const int* ei, int is32, int E, int e) {
  return is32 ? ei[E + e] : ei[2 * (E + e)];
}

__global__ __launch_bounds__(256) void deg_kernel(const int* __restrict__ ei,
                                                  const int* __restrict__ flag,
                                                  int E, int N, int* __restrict__ deg) {
  int e = blockIdx.x * 256 + threadIdx.x;
  if (e >= E + N) return;
  int d = (e < E) ? load_dst(ei, *flag, E, e) : (e - E);
  atomicAdd(&deg[d], 1);
}

// 3-phase parallel scan: per-block scan -> top scan -> add offsets
__global__ __launch_bounds__(256) void scan_blk_kernel(const int* __restrict__ deg,
                                                       int* __restrict__ rowptr,
                                                       int* __restrict__ bsum, int N) {
  __shared__ int buf[256];
  int b = blockIdx.x, t = threadIdx.x, i = b * 256 + t;
  int v = (i < N) ? deg[i] : 0;
  buf[t] = v;
  __syncthreads();
  for (int off = 1; off < 256; off <<= 1) {
    int add = (t >= off) ? buf[t - off] : 0;
    __syncthreads();
    buf[t] += add;
    __syncthreads();
  }
  if (i < N) rowptr[i + 1] = buf[t];
  if (t == 255) bsum[b] = buf[255];
  if (b == 0 && t == 0) rowptr[0] = 0;
}

__global__ __launch_bounds__(256) void scan_top_kernel(int* __restrict__ bsum, int NB) {
  __shared__ int buf[256];
  int t = threadIdx.x;
  int v = (t < NB) ? bsum[t] : 0;
  buf[t] = v;
  __syncthreads();
  for (int off = 1; off < 256; off <<= 1) {
    int add = (t >= off) ? buf[t - off] : 0;
    __syncthreads();
    buf[t] += add;
    __syncthreads();
  }
  if (t < NB) bsum[t] = buf[t];
}

__global__ __launch_bounds__(256) void scan_add_kernel(int* __restrict__ rowptr,
                                                       const int* __restrict__ bsum, int N) {
  int b = blockIdx.x, t = threadIdx.x, i = b * 256 + t;
  if (b > 0 && i < N) rowptr[i + 1] += bsum[b - 1];
}

__global__ __launch_bounds__(256) void fill_kernel(const int* __restrict__ ei,
                                                   const int* __restrict__ flag,
                                                   int E, int N,
                                                   const int* __restrict__ rowptr,
                                                   int* __restrict__ fillc,
                                                   int* __restrict__ colbuf) {
  int e = blockIdx.x * 256 + threadIdx.x;
  if (e >= E + N) return;
  int s, d;
  if (e < E) { int is32 = *flag; s = load_src(ei, is32, E, e); d = load_dst(ei, is32, E, e); }
  else { s = e - E; d = s; }
  int pos = atomicAdd(&fillc[d], 1);
  colbuf[rowptr[d] + pos] = s;
}

// ---------------------------------------------------------------------------
// prep kernels
// ---------------------------------------------------------------------------
// fp32 [n_real] -> hi/lo bf16 (zero padded to n_total)
__global__ __launch_bounds__(256) void split_h_kernel(const float* __restrict__ h,
                                                      ushort_t* __restrict__ hi,
                                                      ushort_t* __restrict__ lo,
                                                      int n_real, int n_total) {
  int i = (blockIdx.x * 256 + threadIdx.x) * 4;
  if (i >= n_total) return;
  f32x4v v = (i < n_real) ? *(const f32x4v*)&h[i] : f32x4v{0.f, 0.f, 0.f, 0.f};
  ushort4v h4, l4;
#pragma unroll
  for (int k = 0; k < 4; ++k) {
    float f = v[k];
    ushort_t hb = f_to_bf16(f);
    h4[k] = hb;
    l4[k] = f_to_bf16(f - bf16_to_f(hb));
  }
  *(ushort4v*)&hi[i] = h4;
  *(ushort4v*)&lo[i] = l4;
}

// Wp [K=128][128] fp32 -> Bt hi/lo [128][128]
__global__ __launch_bounds__(256) void split_wt_kernel(const float* __restrict__ W,
                                                       ushort_t* __restrict__ hi,
                                                       ushort_t* __restrict__ lo,
                                                       int Nn) {
  int t = blockIdx.x * 256 + threadIdx.x;
  if (t >= 128 * Nn) return;
  int n = t >> 7, k = t & 127;
  float f = W[(size_t)k * Nn + n];
  ushort_t hb = f_to_bf16(f);
  hi[t] = hb;
  lo[t] = f_to_bf16(f - bf16_to_f(hb));
}

// W [128][512] fp32 -> Bstack hi/lo [d=128][c=512] with Bt[d][h*128+f] = 0.25*W[f][h*128+d]
__global__ __launch_bounds__(256) void split_wstack_kernel(const float* __restrict__ W,
                                                           ushort_t* __restrict__ hi,
                                                           ushort_t* __restrict__ lo) {
  int t = blockIdx.x * 256 + threadIdx.x;   // 65536 threads
  int d = t >> 9, c = t & 511;
  int h = c >> 7, f = c & 127;
  float v = 0.25f * W[(size_t)f * 512 + h * 128 + d];
  ushort_t hb = f_to_bf16(v);
  hi[t] = hb;
  lo[t] = f_to_bf16(v - bf16_to_f(hb));
}

// Ws[f*4+h] = sum_d W[f, h*128+d] * a_src[h, d]
__global__ __launch_bounds__(512) void wsd_kernel(const float* __restrict__ W,
                                                  const float* __restrict__ a_src,
                                                  const float* __restrict__ a_dst,
                                                  float* __restrict__ Ws,
                                                  float* __restrict__ Wd) {
  int f = threadIdx.x >> 2;
  int h = threadIdx.x & 3;
  float s = 0.f, d = 0.f;
  for (int dd = 0; dd < 128; ++dd) {
    float w = W[f * 512 + h * 128 + dd];
    s += w * a_src[h * 128 + dd];
    d += w * a_dst[h * 128 + dd];
  }
  Ws[f * 4 + h] = s;
  Wd[f * 4 + h] = d;
}

// al_src/al_dst [N,4] from h stored as hi/lo bf16. One wave per node.
__global__ __launch_bounds__(256) void al_kernel_hl(const ushort_t* __restrict__ hhi,
                                                    const ushort_t* __restrict__ hlo,
                                                    const float* __restrict__ Ws,
                                                    const float* __restrict__ Wd,
                                                    float* __restrict__ al_src,
                                                    float* __restrict__ al_dst, int N) {
  __shared__ float sWs[512], sWd[512];
  int t = threadIdx.x;
  sWs[t] = Ws[t]; sWs[t + 256] = Ws[t + 256];
  sWd[t] = Wd[t]; sWd[t + 256] = Wd[t + 256];
  __syncthreads();
  int wave = t >> 6, lane = t & 63;
  int n = blockIdx.x * 4 + wave;
  if (n >= N) return;
  unsigned int uh = *(const unsigned int*)&hhi[(size_t)n * 128 + lane * 2];
  unsigned int ul = *(const unsigned int*)&hlo[(size_t)n * 128 + lane * 2];
  float v0 = bf16_to_f((ushort_t)(uh & 0xffff)) + bf16_to_f((ushort_t)(ul & 0xffff));
  float v1 = bf16_to_f((ushort_t)(uh >> 16)) + bf16_to_f((ushort_t)(ul >> 16));
  float p[8];
#pragma unroll
  for (int hh = 0; hh < 4; ++hh) {
    p[hh]     = v0 * sWs[(2 * lane) * 4 + hh] + v1 * sWs[(2 * lane + 1) * 4 + hh];
    p[4 + hh] = v0 * sWd[(2 * lane) * 4 + hh] + v1 * sWd[(2 * lane + 1) * 4 + hh];
  }
#pragma unroll
  for (int off = 32; off; off >>= 1)
#pragma unroll
    for (int i = 0; i < 8; ++i) p[i] += __shfl_xor(p[i], off);
  if (lane == 0) {
#pragma unroll
    for (int hh = 0; hh < 4; ++hh) {
      al_src[n * 4 + hh] = p[hh];
      al_dst[n * 4 + hh] = p[4 + hh];
    }
  }
}

// ---------------------------------------------------------------------------
// aggregation in h-space: G[n, head*128+f] = sum_s alpha[head] * h[s,f]
// One wave per node; lane owns 2 f-elems; 4 head-accumulators per lane.
// Output written as bf16 hi/lo (feeds MFMA GEMM directly).
// ---------------------------------------------------------------------------
__global__ __launch_bounds__(256) void agg_G_kernel(const ushort_t* __restrict__ hhi,
                                                    const ushort_t* __restrict__ hlo,
                                                    const float* __restrict__ al_src,
                                                    const float* __restrict__ al_dst,
                                                    const int* __restrict__ rowptr,
                                                    const int* __restrict__ colbuf,
                                                    ushort_t* __restrict__ Ghi,
                                                    ushort_t* __restrict__ Glo, int N) {
  int wave = threadIdx.x >> 6, lane = threadIdx.x & 63;
  int n = blockIdx.x * 4 + wave;
  if (n >= N) return;
  int beg = rowptr[n], end = rowptr[n + 1];
  float4 ald = *(const float4*)&al_dst[n * 4];
  float m0 = -1e30f, m1 = -1e30f, m2 = -1e30f, m3 = -1e30f;
  for (int j = beg; j < end; ++j) {
    int s = colbuf[j];
    float4 as = *(const float4*)&al_src[s * 4];
    float e0 = as.x + ald.x; e0 = e0 > 0.f ? e0 : 0.2f * e0; m0 = fmaxf(m0, e0);
    float e1 = as.y + ald.y; e1 = e1 > 0.f ? e1 : 0.2f * e1; m1 = fmaxf(m1, e1);
    float e2 = as.z + ald.z; e2 = e2 > 0.f ? e2 : 0.2f * e2; m2 = fmaxf(m2, e2);
    float e3 = as.w + ald.w; e3 = e3 > 0.f ? e3 : 0.2f * e3; m3 = fmaxf(m3, e3);
  }
  float a00 = 0.f, a01 = 0.f, a10 = 0.f, a11 = 0.f;
  float a20 = 0.f, a21 = 0.f, a30 = 0.f, a31 = 0.f;
  float ss0 = 0.f, ss1 = 0.f, ss2 = 0.f, ss3 = 0.f;
  for (int j = beg; j < end; ++j) {
    int s = colbuf[j];
    float4 as = *(const float4*)&al_src[s * 4];
    float e0 = as.x + ald.x; e0 = e0 > 0.f ? e0 : 0.2f * e0;
    float e1 = as.y + ald.y; e1 = e1 > 0.f ? e1 : 0.2f * e1;
    float e2 = as.z + ald.z; e2 = e2 > 0.f ? e2 : 0.2f * e2;
    float e3 = as.w + ald.w; e3 = e3 > 0.f ? e3 : 0.2f * e3;
    float w0 = __expf(e0 - m0); ss0 += w0;
    float w1 = __expf(e1 - m1); ss1 += w1;
    float w2 = __expf(e2 - m2); ss2 += w2;
    float w3 = __expf(e3 - m3); ss3 += w3;
    unsigned int uh = *(const unsigned int*)&hhi[(size_t)s * 128 + lane * 2];
    unsigned int ul = *(const unsigned int*)&hlo[(size_t)s * 128 + lane * 2];
    float v0 = bf16_to_f((ushort_t)(uh & 0xffff)) + bf16_to_f((ushort_t)(ul & 0xffff));
    float v1 = bf16_to_f((ushort_t)(uh >> 16)) + bf16_to_f((ushort_t)(ul >> 16));
    a00 += w0 * v0; a01 += w0 * v1;
    a10 += w1 * v0; a11 += w1 * v1;
    a20 += w2 * v0; a21 += w2 * v1;
    a30 += w3 * v0; a31 += w3 * v1;
  }
  float inv0 = 1.f / (ss0 + 1e-16f);
  float inv1 = 1.f / (ss1 + 1e-16f);
  float inv2 = 1.f / (ss2 + 1e-16f);
  float inv3 = 1.f / (ss3 + 1e-16f);
  float g[4][2] = {{a00 * inv0, a01 * inv0}, {a10 * inv1, a11 * inv1},
                   {a20 * inv2, a21 * inv2}, {a30 * inv3, a31 * inv3}};
#pragma unroll
  for (int h = 0; h < 4; ++h) {
    ushort_t hi0 = f_to_bf16(g[h][0]);
    ushort_t hi1 = f_to_bf16(g[h][1]);
    ushort_t lo0 = f_to_bf16(g[h][0] - bf16_to_f(hi0));
    ushort_t lo1 = f_to_bf16(g[h][1] - bf16_to_f(hi1));
    size_t o = (size_t)n * 512 + h * 128 + lane * 2;
    *(unsigned int*)&Ghi[o] = (unsigned int)hi0 | ((unsigned int)hi1 << 16);
    *(unsigned int*)&Glo[o] = (unsigned int)lo0 | ((unsigned int)lo1 << 16);
  }
}

// ---------------------------------------------------------------------------
// MFMA GEMM: C[M,128] = A[Mp,K] @ Bt[128,K]^T  (split-bf16 3-pass)
// 128x128 tile/block, 4 waves 2x2, K-loop in 128-wide LDS-staged tiles.
// Output either fp32 (Cf) or bf16 hi/lo pair (Chi/Clo), optional bias/relu.
// ---------------------------------------------------------------------------
__global__ __launch_bounds__(256) void mfma_gemm_kernel(
    const ushort_t* __restrict__ Ahi, const ushort_t* __restrict__ Alo,
    const ushort_t* __restrict__ Bthi, const ushort_t* __restrict__ Btlo,
    int K, float* __restrict__ Cf,
    ushort_t* __restrict__ Chi, ushort_t* __restrict__ Clo,
    int M, const float* __restrict__ bias, int relu) {
  __shared__ ushort_t As[2][128 * 128];  // 64 KB
  int tid = threadIdx.x;
  int wave = tid >> 6, lane = tid & 63;
  int wr = wave >> 1, wc = wave & 1;
  int row0 = blockIdx.x * 128;
  int krow = lane >> 4, ml = lane & 15;
  f32x4 acc[4][4] = {};

  for (int ko = 0; ko < K; ko += 128) {
#pragma unroll
    for (int p = 0; p < 2; ++p) {
      const ushort_t* src = p ? Alo : Ahi;
#pragma unroll
      for (int it = 0; it < 8; ++it) {
        int chunk = wave + it * 4;            // wave-uniform
        int row = chunk * 4 + (lane >> 4);
        int sp = lane & 15;
        int sl = sp ^ (row & 7);              // source-side swizzle, linear LDS dest
        gload_lds16(src + (size_t)(row0 + row) * K + ko + sl * 8,
                    &As[p][chunk * 512]);
      }
    }
    __syncthreads();
#pragma unroll
    for (int kt = 0; kt < 4; ++kt) {
      short8 ah[4], al_[4], bh[4], bl[4];
      int sl = kt * 4 + krow;
#pragma unroll
      for (int f = 0; f < 4; ++f) {
        int row = wr * 64 + f * 16 + ml;
        int phys = sl ^ (row & 7);
        int off = row * 128 + phys * 8;
        ah[f]  = *(const short8*)&As[0][off];
        al_[f] = *(const short8*)&As[1][off];
      }
      int k0 = ko + kt * 32 + krow * 8;
#pragma unroll
      for (int f = 0; f < 4; ++f) {
        int nn = wc * 64 + f * 16 + ml;
        bh[f] = *(const short8*)&Bthi[(size_t)nn * K + k0];
        bl[f] = *(const short8*)&Btlo[(size_t)nn * K + k0];
      }
#pragma unroll
      for (int i = 0; i < 4; ++i)
#pragma unroll
        for (int j = 0; j < 4; ++j) {
          acc[i][j] = __builtin_amdgcn_mfma_f32_16x16x32_bf16(ah[i],  bh[j], acc[i][j], 0, 0, 0);
          acc[i][j] = __builtin_amdgcn_mfma_f32_16x16x32_bf16(ah[i],  bl[j], acc[i][j], 0, 0, 0);
          acc[i][j] = __builtin_amdgcn_mfma_f32_16x16x32_bf16(al_[i], bh[j], acc[i][j], 0, 0, 0);
        }
    }
    __syncthreads();
  }

  // epilogue: C/D layout col=lane&15, row=(lane>>4)*4+reg
#pragma unroll
  for (int j = 0; j < 4; ++j) {
    int col = wc * 64 + j * 16 + ml;
    float bv = bias ? bias[col] : 0.f;
#pragma unroll
    for (int i = 0; i < 4; ++i) {
#pragma unroll
      for (int r = 0; r < 4; ++r) {
        int row = row0 + wr * 64 + i * 16 + krow * 4 + r;
        if (row < M) {
          float v = acc[i][j][r] + bv;
          if (relu) v = fmaxf(v, 0.f);
          if (Cf) {
            Cf[(size_t)row * 128 + col] = v;
          } else {
            ushort_t hb = f_to_bf16(v);
            Chi[(size_t)row * 128 + col] = hb;
            Clo[(size_t)row * 128 + col] = f_to_bf16(v - bf16_to_f(hb));
          }
        }
      }
    }
  }
}

// ---------------------------------------------------------------------------
extern "C" void kernel_launch(void* const* d_in, const int* in_sizes, int n_in,
                              void* d_out, int out_size, void* d_ws, size_t ws_size,
                              hipStream_t stream) {
  const float* x  = (const float*)d_in[0];
  const int*   ei = (const int*)d_in[1];
  const float* Wl[3]  = {(const float*)d_in[2], (const float*)d_in[6], (const float*)d_in[10]};
  const float* asr[3] = {(const float*)d_in[3], (const float*)d_in[7], (const float*)d_in[11]};
  const float* adr[3] = {(const float*)d_in[4], (const float*)d_in[8], (const float*)d_in[12]};
  const float* bl[3]  = {(const float*)d_in[5], (const float*)d_in[9], (const float*)d_in[13]};
  const float* Wp = (const float*)d_in[14];
  const float* bp = (const float*)d_in[15];

  const int N = in_sizes[0] / 128;   // 50000
  const int E = in_sizes[1] / 2;     // 400000
  const int EN = E + N;
  const int Mtiles = (N + 127) / 128;  // 391
  const int Mp = Mtiles * 128;         // 50048
  const int NB = (N + 255) / 256;      // scan blocks

  char* ws = (char*)d_ws;
  size_t off = 0;
  auto carve = [&](size_t bytes) -> void* {
    void* p = ws + off;
    off = (off + bytes + 255) & ~(size_t)255;
    return p;
  };
  ushort_t* Ghi   = (ushort_t*)carve((size_t)Mp * 512 * 2);  // 51.2 MB
  ushort_t* Glo   = (ushort_t*)carve((size_t)Mp * 512 * 2);
  ushort_t* hAhi  = (ushort_t*)carve((size_t)Mp * 128 * 2);  // 12.8 MB each
  ushort_t* hAlo  = (ushort_t*)carve((size_t)Mp * 128 * 2);
  ushort_t* hBhi  = (ushort_t*)carve((size_t)Mp * 128 * 2);
  ushort_t* hBlo  = (ushort_t*)carve((size_t)Mp * 128 * 2);
  ushort_t* wshi  = (ushort_t*)carve((size_t)128 * 512 * 2);
  ushort_t* wslo  = (ushort_t*)carve((size_t)128 * 512 * 2);
  float*    alsrc = (float*)carve((size_t)N * 4 * 4);
  float*    aldst = (float*)carve((size_t)N * 4 * 4);
  float*    Wsb   = (float*)carve(512 * 4);
  float*    Wdb   = (float*)carve(512 * 4);
  int*      rowptr= (int*)carve((size_t)(N + 1) * 4);
  int*      deg   = (int*)carve((size_t)N * 4);
  int*      bsum  = (int*)carve(256 * 4);
  int*      fillc = (int*)carve((size_t)N * 4);
  int*      colbuf= (int*)carve((size_t)EN * 4);
  int*      flag  = (int*)carve(256);

  // ---- CSR build ----
  detect_i64_kernel<<<1, 64, 0, stream>>>(ei, flag);
  hipMemsetAsync(deg, 0, (size_t)N * 4, stream);
  hipMemsetAsync(fillc, 0, (size_t)N * 4, stream);
  int ebl = (EN + 255) / 256;
  deg_kernel<<<ebl, 256, 0, stream>>>(ei, flag, E, N, deg);
  scan_blk_kernel<<<NB, 256, 0, stream>>>(deg, rowptr, bsum, N);
  scan_top_kernel<<<1, 256, 0, stream>>>(bsum, NB);
  scan_add_kernel<<<NB, 256, 0, stream>>>(rowptr, bsum, N);
  fill_kernel<<<ebl, 256, 0, stream>>>(ei, flag, E, N, rowptr, fillc, colbuf);

  // ---- split x into bf16 hi/lo ----
  const int n_real = N * 128, n_total = Mp * 128;
  split_h_kernel<<<(n_total / 4 + 255) / 256, 256, 0, stream>>>(x, hAhi, hAlo, n_real, n_total);

  // ---- 3 GAT layers ----
  ushort_t *inhi = hAhi, *inlo = hAlo, *outhi = hBhi, *outlo = hBlo;
  for (int L = 0; L < 3; ++L) {
    wsd_kernel<<<1, 512, 0, stream>>>(Wl[L], asr[L], adr[L], Wsb, Wdb);
    al_kernel_hl<<<(N + 3) / 4, 256, 0, stream>>>(inhi, inlo, Wsb, Wdb, alsrc, aldst, N);
    agg_G_kernel<<<(N + 3) / 4, 256, 0, stream>>>(inhi, inlo, alsrc, aldst,
                                                  rowptr, colbuf, Ghi, Glo, N);
    split_wstack_kernel<<<(128 * 512) / 256, 256, 0, stream>>>(Wl[L], wshi, wslo);
    mfma_gemm_kernel<<<Mtiles, 256, 0, stream>>>(Ghi, Glo, wshi, wslo, 512,
                                                 nullptr, outhi, outlo, N, bl[L], 1);
    ushort_t* t;
    t = inhi; inhi = outhi; outhi = t;
    t = inlo; inlo = outlo; outlo = t;
  }

  // ---- final projection: out = h3 @ Wp + bp (fp32 out) ----
  split_wt_kernel<<<(128 * 128) / 256, 256, 0, stream>>>(Wp, wshi, wslo, 128);
  mfma_gemm_kernel<<<Mtiles, 256, 0, stream>>>(inhi, inlo, wshi, wslo, 128,
                                               (float*)d_out, nullptr, nullptr, N, bp, 0);
}

// Round 4
// 690.458 us; speedup vs baseline: 2.0772x; 1.2073x over previous
//
#include <hip/hip_runtime.h>
#include <cstddef>
#include <cstdint>

typedef short short8 __attribute__((ext_vector_type(8)));
typedef float f32x4 __attribute__((ext_vector_type(4)));
typedef unsigned short ushort_t;
typedef unsigned int uint_t;
typedef float f32x4v __attribute__((ext_vector_type(4)));

__device__ __forceinline__ float bf16_to_f(ushort_t u) {
  union { unsigned int i; float f; } v; v.i = ((unsigned int)u) << 16; return v.f;
}
__device__ __forceinline__ float lo16f(uint_t u) {   // low 16 bits = hi bf16 part
  union { uint_t i; float f; } v; v.i = u << 16; return v.f;
}
__device__ __forceinline__ float hi16f(uint_t u) {   // high 16 bits = lo bf16 part
  union { uint_t i; float f; } v; v.i = u & 0xffff0000u; return v.f;
}
__device__ __forceinline__ ushort_t f_to_bf16(float f) {
  union { float ff; unsigned int i; } v; v.ff = f;
  unsigned int x = v.i;
  unsigned int lsb = (x >> 16) & 1u;
  x += 0x7fffu + lsb;               // round-to-nearest-even
  return (ushort_t)(x >> 16);
}
__device__ __forceinline__ uint_t pack_hl(float f) {
  ushort_t hb = f_to_bf16(f);
  ushort_t lb = f_to_bf16(f - bf16_to_f(hb));
  return (uint_t)hb | ((uint_t)lb << 16);
}

__device__ __forceinline__ void gload_lds16(const void* g, void* l) {
  __builtin_amdgcn_global_load_lds((const __attribute__((address_space(1))) void*)g,
                                   (__attribute__((address_space(3))) void*)l, 16, 0, 0);
}

// ---------------------------------------------------------------------------
// CSR build
// ---------------------------------------------------------------------------
__global__ __launch_bounds__(64) void detect_i64_kernel(const int* __restrict__ ei,
                                                        int* __restrict__ flag) {
  if (threadIdx.x == 0) {
    int is32 = 0;
    for (int i = 1; i < 1001; i += 2) {
      if (ei[i] != 0) { is32 = 1; break; }
    }
    *flag = is32;
  }
}

__device__ __forceinline__ int load_src(const int* ei, int is32, int E, int e) {
  return is32 ? ei[e] : ei[2 * e];
}
__device__ __forceinline__ int load_dst(const int* ei, int is32, int E, int e) {
  return is32 ? ei[E + e] : ei[2 * (E + e)];
}

__global__ __launch_bounds__(256) void deg_kernel(const int* __restrict__ ei,
                                                  const int* __restrict__ flag,
                                                  int E, int N, int* __restrict__ deg) {
  int e = blockIdx.x * 256 + threadIdx.x;
  if (e >= E + N) return;
  int d = (e < E) ? load_dst(ei, *flag, E, e) : (e - E);
  atomicAdd(&deg[d], 1);
}

__global__ __launch_bounds__(256) void scan_blk_kernel(const int* __restrict__ deg,
                                                       int* __restrict__ rowptr,
                                                       int* __restrict__ bsum, int N) {
  __shared__ int buf[256];
  int b = blockIdx.x, t = threadIdx.x, i = b * 256 + t;
  int v = (i < N) ? deg[i] : 0;
  buf[t] = v;
  __syncthreads();
  for (int off = 1; off < 256; off <<= 1) {
    int add = (t >= off) ? buf[t - off] : 0;
    __syncthreads();
    buf[t] += add;
    __syncthreads();
  }
  if (i < N) rowptr[i + 1] = buf[t];
  if (t == 255) bsum[b] = buf[255];
  if (b == 0 && t == 0) rowptr[0] = 0;
}

__global__ __launch_bounds__(256) void scan_top_kernel(int* __restrict__ bsum, int NB) {
  __shared__ int buf[256];
  int t = threadIdx.x;
  int v = (t < NB) ? bsum[t] : 0;
  buf[t] = v;
  __syncthreads();
  for (int off = 1; off < 256; off <<= 1) {
    int add = (t >= off) ? buf[t - off] : 0;
    __syncthreads();
    buf[t] += add;
    __syncthreads();
  }
  if (t < NB) bsum[t] = buf[t];
}

__global__ __launch_bounds__(256) void scan_add_kernel(int* __restrict__ rowptr,
                                                       const int* __restrict__ bsum, int N) {
  int b = blockIdx.x, t = threadIdx.x, i = b * 256 + t;
  if (b > 0 && i < N) rowptr[i + 1] += bsum[b - 1];
}

__global__ __launch_bounds__(256) void fill_kernel(const int* __restrict__ ei,
                                                   const int* __restrict__ flag,
                                                   int E, int N,
                                                   const int* __restrict__ rowptr,
                                                   int* __restrict__ fillc,
                                                   int* __restrict__ colbuf) {
  int e = blockIdx.x * 256 + threadIdx.x;
  if (e >= E + N) return;
  int s, d;
  if (e < E) { int is32 = *flag; s = load_src(ei, is32, E, e); d = load_dst(ei, is32, E, e); }
  else { s = e - E; d = s; }
  int pos = atomicAdd(&fillc[d], 1);
  colbuf[rowptr[d] + pos] = s;
}

// ---------------------------------------------------------------------------
// prep kernels
// ---------------------------------------------------------------------------
// fp32 -> interleaved packed (hi|lo<<16) uint per element
__global__ __launch_bounds__(256) void split_x_i_kernel(const float* __restrict__ h,
                                                        uint_t* __restrict__ hi,
                                                        int n) {
  int i = (blockIdx.x * 256 + threadIdx.x) * 4;
  if (i >= n) return;
  f32x4v v = *(const f32x4v*)&h[i];
  uint4 o;
  o.x = pack_hl(v[0]); o.y = pack_hl(v[1]); o.z = pack_hl(v[2]); o.w = pack_hl(v[3]);
  *(uint4*)&hi[i] = o;
}

// Wp [K=128][128] fp32 -> Bt hi/lo [128][128]
__global__ __launch_bounds__(256) void split_wt_kernel(const float* __restrict__ W,
                                                       ushort_t* __restrict__ hi,
                                                       ushort_t* __restrict__ lo,
                                                       int Nn) {
  int t = blockIdx.x * 256 + threadIdx.x;
  if (t >= 128 * Nn) return;
  int n = t >> 7, k = t & 127;
  float f = W[(size_t)k * Nn + n];
  ushort_t hb = f_to_bf16(f);
  hi[t] = hb;
  lo[t] = f_to_bf16(f - bf16_to_f(hb));
}

// W [128][512] fp32 -> Bstack hi/lo [d=128][c=512] with Bt[d][h*128+f] = 0.25*W[f][h*128+d]
__global__ __launch_bounds__(256) void split_wstack_kernel(const float* __restrict__ W,
                                                           ushort_t* __restrict__ hi,
                                                           ushort_t* __restrict__ lo) {
  int t = blockIdx.x * 256 + threadIdx.x;   // 65536 threads
  int d = t >> 9, c = t & 511;
  int h = c >> 7, f = c & 127;
  float v = 0.25f * W[(size_t)f * 512 + h * 128 + d];
  ushort_t hb = f_to_bf16(v);
  hi[t] = hb;
  lo[t] = f_to_bf16(v - bf16_to_f(hb));
}

// Ws[f*4+h] = sum_d W[f, h*128+d] * a_src[h, d]
__global__ __launch_bounds__(512) void wsd_kernel(const float* __restrict__ W,
                                                  const float* __restrict__ a_src,
                                                  const float* __restrict__ a_dst,
                                                  float* __restrict__ Ws,
                                                  float* __restrict__ Wd) {
  int f = threadIdx.x >> 2;
  int h = threadIdx.x & 3;
  float s = 0.f, d = 0.f;
  for (int dd = 0; dd < 128; ++dd) {
    float w = W[f * 512 + h * 128 + dd];
    s += w * a_src[h * 128 + dd];
    d += w * a_dst[h * 128 + dd];
  }
  Ws[f * 4 + h] = s;
  Wd[f * 4 + h] = d;
}

// al_src/al_dst [N,4] from interleaved h. One wave per node.
__global__ __launch_bounds__(256) void al_kernel_i(const uint_t* __restrict__ hint,
                                                   const float* __restrict__ Ws,
                                                   const float* __restrict__ Wd,
                                                   float* __restrict__ al_src,
                                                   float* __restrict__ al_dst, int N) {
  __shared__ float sWs[512], sWd[512];
  int t = threadIdx.x;
  sWs[t] = Ws[t]; sWs[t + 256] = Ws[t + 256];
  sWd[t] = Wd[t]; sWd[t + 256] = Wd[t + 256];
  __syncthreads();
  int wave = t >> 6, lane = t & 63;
  int n = blockIdx.x * 4 + wave;
  if (n >= N) return;
  uint2 uu = *(const uint2*)&hint[(size_t)n * 128 + lane * 2];
  float v0 = lo16f(uu.x) + hi16f(uu.x);
  float v1 = lo16f(uu.y) + hi16f(uu.y);
  float p[8];
#pragma unroll
  for (int hh = 0; hh < 4; ++hh) {
    p[hh]     = v0 * sWs[(2 * lane) * 4 + hh] + v1 * sWs[(2 * lane + 1) * 4 + hh];
    p[4 + hh] = v0 * sWd[(2 * lane) * 4 + hh] + v1 * sWd[(2 * lane + 1) * 4 + hh];
  }
#pragma unroll
  for (int off = 32; off; off >>= 1)
#pragma unroll
    for (int i = 0; i < 8; ++i) p[i] += __shfl_xor(p[i], off);
  if (lane == 0) {
#pragma unroll
    for (int hh = 0; hh < 4; ++hh) {
      al_src[n * 4 + hh] = p[hh];
      al_dst[n * 4 + hh] = p[4 + hh];
    }
  }
}

// ---------------------------------------------------------------------------
// aggregation: G[n, head*128+f] = softmax-weighted sum of h[s,f]
// 2 nodes per wave (32-lane halves), single-pass online softmax.
// Lane owns 4 feature elems (one uint4 of interleaved h per edge).
// ---------------------------------------------------------------------------
__global__ __launch_bounds__(512) void agg_G_kernel(const uint_t* __restrict__ hint,
                                                    const float* __restrict__ al_src,
                                                    const float* __restrict__ al_dst,
                                                    const int* __restrict__ rowptr,
                                                    const int* __restrict__ colbuf,
                                                    ushort_t* __restrict__ Ghi,
                                                    ushort_t* __restrict__ Glo, int N) {
  int wave = threadIdx.x >> 6, lane = threadIdx.x & 63;
  int fl = lane & 31;
  int n = blockIdx.x * 16 + wave * 2 + (lane >> 5);
  bool alive = n < N;
  int beg = 0, d = 0;
  float4 ald = make_float4(0.f, 0.f, 0.f, 0.f);
  if (alive) {
    beg = rowptr[n];
    d = rowptr[n + 1] - beg;
    ald = *(const float4*)&al_dst[(size_t)n * 4];
  }
  int dmax = max(d, __shfl_xor(d, 32));
  float m[4], ss[4], acc[4][4];
#pragma unroll
  for (int h = 0; h < 4; ++h) {
    m[h] = -1e30f; ss[h] = 0.f;
#pragma unroll
    for (int k = 0; k < 4; ++k) acc[h][k] = 0.f;
  }
  for (int it = 0; it < dmax; ++it) {
    bool valid = it < d;                       // d==0 when !alive
    int s = colbuf[valid ? beg + it : beg];
    float4 as = *(const float4*)&al_src[(size_t)s * 4];
    uint4 hv = *(const uint4*)&hint[(size_t)s * 128 + fl * 4];
    float e[4];
    e[0] = as.x + ald.x; e[1] = as.y + ald.y; e[2] = as.z + ald.z; e[3] = as.w + ald.w;
#pragma unroll
    for (int h = 0; h < 4; ++h) {
      e[h] = e[h] > 0.f ? e[h] : 0.2f * e[h];
      e[h] = valid ? e[h] : -1e30f;
    }
    if (__any(e[0] > m[0] || e[1] > m[1] || e[2] > m[2] || e[3] > m[3])) {
#pragma unroll
      for (int h = 0; h < 4; ++h) {
        float nm = fmaxf(m[h], e[h]);
        float f = __expf(m[h] - nm);
        m[h] = nm;
        ss[h] *= f;
#pragma unroll
        for (int k = 0; k < 4; ++k) acc[h][k] *= f;
      }
    }
    float v[4];
    v[0] = lo16f(hv.x) + hi16f(hv.x);
    v[1] = lo16f(hv.y) + hi16f(hv.y);
    v[2] = lo16f(hv.z) + hi16f(hv.z);
    v[3] = lo16f(hv.w) + hi16f(hv.w);
#pragma unroll
    for (int h = 0; h < 4; ++h) {
      float w = __expf(e[h] - m[h]);
      ss[h] += w;
#pragma unroll
      for (int k = 0; k < 4; ++k) acc[h][k] += w * v[k];
    }
  }
  if (!alive) return;
#pragma unroll
  for (int h = 0; h < 4; ++h) {
    float inv = 1.f / (ss[h] + 1e-16f);
    float g0 = acc[h][0] * inv, g1 = acc[h][1] * inv;
    float g2 = acc[h][2] * inv, g3 = acc[h][3] * inv;
    ushort_t h0 = f_to_bf16(g0), h1 = f_to_bf16(g1), h2 = f_to_bf16(g2), h3 = f_to_bf16(g3);
    ushort_t l0 = f_to_bf16(g0 - bf16_to_f(h0)), l1 = f_to_bf16(g1 - bf16_to_f(h1));
    ushort_t l2 = f_to_bf16(g2 - bf16_to_f(h2)), l3 = f_to_bf16(g3 - bf16_to_f(h3));
    size_t o = (size_t)n * 512 + h * 128 + fl * 4;
    *(uint2*)&Ghi[o] = make_uint2((uint_t)h0 | ((uint_t)h1 << 16),
                                  (uint_t)h2 | ((uint_t)h3 << 16));
    *(uint2*)&Glo[o] = make_uint2((uint_t)l0 | ((uint_t)l1 << 16),
                                  (uint_t)l2 | ((uint_t)l3 << 16));
  }
}

// ---------------------------------------------------------------------------
// MFMA GEMM: C[M,128] = A[Mp,K] @ Bt[128,K]^T  (split-bf16 3-pass)
// Output: fp32 Cf, or interleaved packed uint Ci, or separate hi/lo.
// ---------------------------------------------------------------------------
__global__ __launch_bounds__(256) void mfma_gemm_kernel(
    const ushort_t* __restrict__ Ahi, const ushort_t* __restrict__ Alo,
    const ushort_t* __restrict__ Bthi, const ushort_t* __restrict__ Btlo,
    int K, float* __restrict__ Cf, uint_t* __restrict__ Ci,
    ushort_t* __restrict__ Chi, ushort_t* __restrict__ Clo,
    int M, const float* __restrict__ bias, int relu) {
  __shared__ ushort_t As[2][128 * 128];  // 64 KB
  int tid = threadIdx.x;
  int wave = tid >> 6, lane = tid & 63;
  int wr = wave >> 1, wc = wave & 1;
  int row0 = blockIdx.x * 128;
  int krow = lane >> 4, ml = lane & 15;
  f32x4 acc[4][4] = {};

  for (int ko = 0; ko < K; ko += 128) {
#pragma unroll
    for (int p = 0; p < 2; ++p) {
      const ushort_t* src = p ? Alo : Ahi;
#pragma unroll
      for (int it = 0; it < 8; ++it) {
        int chunk = wave + it * 4;            // wave-uniform
        int row = chunk * 4 + (lane >> 4);
        int sp = lane & 15;
        int sl = sp ^ (row & 7);              // source-side swizzle, linear LDS dest
        gload_lds16(src + (size_t)(row0 + row) * K + ko + sl * 8,
                    &As[p][chunk * 512]);
      }
    }
    __syncthreads();
#pragma unroll
    for (int kt = 0; kt < 4; ++kt) {
      short8 ah[4], al_[4], bh[4], bl[4];
      int sl = kt * 4 + krow;
#pragma unroll
      for (int f = 0; f < 4; ++f) {
        int row = wr * 64 + f * 16 + ml;
        int phys = sl ^ (row & 7);
        int off = row * 128 + phys * 8;
        ah[f]  = *(const short8*)&As[0][off];
        al_[f] = *(const short8*)&As[1][off];
      }
      int k0 = ko + kt * 32 + krow * 8;
#pragma unroll
      for (int f = 0; f < 4; ++f) {
        int nn = wc * 64 + f * 16 + ml;
        bh[f] = *(const short8*)&Bthi[(size_t)nn * K + k0];
        bl[f] = *(const short8*)&Btlo[(size_t)nn * K + k0];
      }
#pragma unroll
      for (int i = 0; i < 4; ++i)
#pragma unroll
        for (int j = 0; j < 4; ++j) {
          acc[i][j] = __builtin_amdgcn_mfma_f32_16x16x32_bf16(ah[i],  bh[j], acc[i][j], 0, 0, 0);
          acc[i][j] = __builtin_amdgcn_mfma_f32_16x16x32_bf16(ah[i],  bl[j], acc[i][j], 0, 0, 0);
          acc[i][j] = __builtin_amdgcn_mfma_f32_16x16x32_bf16(al_[i], bh[j], acc[i][j], 0, 0, 0);
        }
    }
    __syncthreads();
  }

  // epilogue: C/D layout col=lane&15, row=(lane>>4)*4+reg
#pragma unroll
  for (int j = 0; j < 4; ++j) {
    int col = wc * 64 + j * 16 + ml;
    float bv = bias ? bias[col] : 0.f;
#pragma unroll
    for (int i = 0; i < 4; ++i) {
#pragma unroll
      for (int r = 0; r < 4; ++r) {
        int row = row0 + wr * 64 + i * 16 + krow * 4 + r;
        if (row < M) {
          float v = acc[i][j][r] + bv;
          if (relu) v = fmaxf(v, 0.f);
          if (Cf) {
            Cf[(size_t)row * 128 + col] = v;
          } else if (Ci) {
            Ci[(size_t)row * 128 + col] = pack_hl(v);
          } else {
            ushort_t hb = f_to_bf16(v);
            Chi[(size_t)row * 128 + col] = hb;
            Clo[(size_t)row * 128 + col] = f_to_bf16(v - bf16_to_f(hb));
          }
        }
      }
    }
  }
}

// ---------------------------------------------------------------------------
extern "C" void kernel_launch(void* const* d_in, const int* in_sizes, int n_in,
                              void* d_out, int out_size, void* d_ws, size_t ws_size,
                              hipStream_t stream) {
  const float* x  = (const float*)d_in[0];
  const int*   ei = (const int*)d_in[1];
  const float* Wl[3]  = {(const float*)d_in[2], (const float*)d_in[6], (const float*)d_in[10]};
  const float* asr[3] = {(const float*)d_in[3], (const float*)d_in[7], (const float*)d_in[11]};
  const float* adr[3] = {(const float*)d_in[4], (const float*)d_in[8], (const float*)d_in[12]};
  const float* bl[3]  = {(const float*)d_in[5], (const float*)d_in[9], (const float*)d_in[13]};
  const float* Wp = (const float*)d_in[14];
  const float* bp = (const float*)d_in[15];

  const int N = in_sizes[0] / 128;   // 50000
  const int E = in_sizes[1] / 2;     // 400000
  const int EN = E + N;
  const int Mtiles = (N + 127) / 128;  // 391
  const int Mp = Mtiles * 128;         // 50048
  const int NB = (N + 255) / 256;      // scan blocks

  char* ws = (char*)d_ws;
  size_t off = 0;
  auto carve = [&](size_t bytes) -> void* {
    void* p = ws + off;
    off = (off + bytes + 255) & ~(size_t)255;
    return p;
  };
  ushort_t* Ghi   = (ushort_t*)carve((size_t)Mp * 512 * 2);  // 51.2 MB
  ushort_t* Glo   = (ushort_t*)carve((size_t)Mp * 512 * 2);
  uint_t*   hiA   = (uint_t*)carve((size_t)N * 128 * 4);     // 25.6 MB (interleaved)
  uint_t*   hiB   = (uint_t*)carve((size_t)N * 128 * 4);     // 25.6 MB
  ushort_t* h3hi  = (ushort_t*)carve((size_t)Mp * 128 * 2);  // 12.8 MB
  ushort_t* h3lo  = (ushort_t*)carve((size_t)Mp * 128 * 2);
  ushort_t* wshi  = (ushort_t*)carve((size_t)128 * 512 * 2);
  ushort_t* wslo  = (ushort_t*)carve((size_t)128 * 512 * 2);
  float*    alsrc = (float*)carve((size_t)N * 4 * 4);
  float*    aldst = (float*)carve((size_t)N * 4 * 4);
  float*    Wsb   = (float*)carve(512 * 4);
  float*    Wdb   = (float*)carve(512 * 4);
  int*      rowptr= (int*)carve((size_t)(N + 1) * 4);
  int*      deg   = (int*)carve((size_t)N * 4);
  int*      bsum  = (int*)carve(256 * 4);
  int*      fillc = (int*)carve((size_t)N * 4);
  int*      colbuf= (int*)carve((size_t)EN * 4);
  int*      flag  = (int*)carve(256);

  // ---- CSR build ----
  detect_i64_kernel<<<1, 64, 0, stream>>>(ei, flag);
  hipMemsetAsync(deg, 0, (size_t)N * 4, stream);
  hipMemsetAsync(fillc, 0, (size_t)N * 4, stream);
  int ebl = (EN + 255) / 256;
  deg_kernel<<<ebl, 256, 0, stream>>>(ei, flag, E, N, deg);
  scan_blk_kernel<<<NB, 256, 0, stream>>>(deg, rowptr, bsum, N);
  scan_top_kernel<<<1, 256, 0, stream>>>(bsum, NB);
  scan_add_kernel<<<NB, 256, 0, stream>>>(rowptr, bsum, N);
  fill_kernel<<<ebl, 256, 0, stream>>>(ei, flag, E, N, rowptr, fillc, colbuf);

  // ---- split x into interleaved packed bf16 hi/lo ----
  const int n_real = N * 128;
  split_x_i_kernel<<<(n_real / 4 + 255) / 256, 256, 0, stream>>>(x, hiA, n_real);

  // ---- 3 GAT layers ----
  uint_t* hin = hiA;
  uint_t* hnext = hiB;
  for (int L = 0; L < 3; ++L) {
    wsd_kernel<<<1, 512, 0, stream>>>(Wl[L], asr[L], adr[L], Wsb, Wdb);
    al_kernel_i<<<(N + 3) / 4, 256, 0, stream>>>(hin, Wsb, Wdb, alsrc, aldst, N);
    agg_G_kernel<<<(N + 15) / 16, 512, 0, stream>>>(hin, alsrc, aldst,
                                                    rowptr, colbuf, Ghi, Glo, N);
    split_wstack_kernel<<<(128 * 512) / 256, 256, 0, stream>>>(Wl[L], wshi, wslo);
    if (L < 2) {
      mfma_gemm_kernel<<<Mtiles, 256, 0, stream>>>(Ghi, Glo, wshi, wslo, 512,
                                                   nullptr, hnext, nullptr, nullptr,
                                                   N, bl[L], 1);
      uint_t* t = hin; hin = hnext; hnext = t;
    } else {
      mfma_gemm_kernel<<<Mtiles, 256, 0, stream>>>(Ghi, Glo, wshi, wslo, 512,
                                                   nullptr, nullptr, h3hi, h3lo,
                                                   N, bl[L], 1);
    }
  }

  // ---- final projection: out = h3 @ Wp + bp (fp32 out) ----
  split_wt_kernel<<<(128 * 128) / 256, 256, 0, stream>>>(Wp, wshi, wslo, 128);
  mfma_gemm_kernel<<<Mtiles, 256, 0, stream>>>(h3hi, h3lo, wshi, wslo, 128,
                                               (float*)d_out, nullptr, nullptr, nullptr,
                                               N, bp, 0);
}

// Round 6
// 529.259 us; speedup vs baseline: 2.7099x; 1.3046x over previous
//
#include <hip/hip_runtime.h>
#include <cstddef>
#include <cstdint>

typedef short short8 __attribute__((ext_vector_type(8)));
typedef float f32x4 __attribute__((ext_vector_type(4)));
typedef unsigned short ushort_t;
typedef unsigned int uint_t;
typedef float f32x4v __attribute__((ext_vector_type(4)));

__device__ __forceinline__ float bf16_to_f(ushort_t u) {
  union { unsigned int i; float f; } v; v.i = ((unsigned int)u) << 16; return v.f;
}
__device__ __forceinline__ float lo16f(uint_t u) {   // low 16 bits = hi bf16 part
  union { uint_t i; float f; } v; v.i = u << 16; return v.f;
}
__device__ __forceinline__ float hi16f(uint_t u) {   // high 16 bits = lo bf16 part
  union { uint_t i; float f; } v; v.i = u & 0xffff0000u; return v.f;
}
__device__ __forceinline__ ushort_t f_to_bf16(float f) {
  union { float ff; unsigned int i; } v; v.ff = f;
  unsigned int x = v.i;
  unsigned int lsb = (x >> 16) & 1u;
  x += 0x7fffu + lsb;               // round-to-nearest-even
  return (ushort_t)(x >> 16);
}
__device__ __forceinline__ uint_t pack_hl(float f) {
  ushort_t hb = f_to_bf16(f);
  ushort_t lb = f_to_bf16(f - bf16_to_f(hb));
  return (uint_t)hb | ((uint_t)lb << 16);
}

__device__ __forceinline__ void gload_lds16(const void* g, void* l) {
  __builtin_amdgcn_global_load_lds((const __attribute__((address_space(1))) void*)g,
                                   (__attribute__((address_space(3))) void*)l, 16, 0, 0);
}

// ---------------------------------------------------------------------------
// CSR build
// ---------------------------------------------------------------------------
__global__ __launch_bounds__(64) void detect_i64_kernel(const int* __restrict__ ei,
                                                        int* __restrict__ flag) {
  if (threadIdx.x == 0) {
    int is32 = 0;
    for (int i = 1; i < 1001; i += 2) {
      if (ei[i] != 0) { is32 = 1; break; }
    }
    *flag = is32;
  }
}

__device__ __forceinline__ int load_src(const int* ei, int is32, int E, int e) {
  return is32 ? ei[e] : ei[2 * e];
}
__device__ __forceinline__ int load_dst(const int* ei, int is32, int E, int e) {
  return is32 ? ei[E + e] : ei[2 * (E + e)];
}

__global__ __launch_bounds__(256) void deg_kernel(const int* __restrict__ ei,
                                                  const int* __restrict__ flag,
                                                  int E, int N, int* __restrict__ deg) {
  int e = blockIdx.x * 256 + threadIdx.x;
  if (e >= E + N) return;
  int d = (e < E) ? load_dst(ei, *flag, E, e) : (e - E);
  atomicAdd(&deg[d], 1);
}

__global__ __launch_bounds__(256) void scan_blk_kernel(const int* __restrict__ deg,
                                                       int* __restrict__ rowptr,
                                                       int* __restrict__ bsum, int N) {
  __shared__ int buf[256];
  int b = blockIdx.x, t = threadIdx.x, i = b * 256 + t;
  int v = (i < N) ? deg[i] : 0;
  buf[t] = v;
  __syncthreads();
  for (int off = 1; off < 256; off <<= 1) {
    int add = (t >= off) ? buf[t - off] : 0;
    __syncthreads();
    buf[t] += add;
    __syncthreads();
  }
  if (i < N) rowptr[i + 1] = buf[t];
  if (t == 255) bsum[b] = buf[255];
  if (b == 0 && t == 0) rowptr[0] = 0;
}

__global__ __launch_bounds__(256) void scan_top_kernel(int* __restrict__ bsum, int NB) {
  __shared__ int buf[256];
  int t = threadIdx.x;
  int v = (t < NB) ? bsum[t] : 0;
  buf[t] = v;
  __syncthreads();
  for (int off = 1; off < 256; off <<= 1) {
    int add = (t >= off) ? buf[t - off] : 0;
    __syncthreads();
    buf[t] += add;
    __syncthreads();
  }
  if (t < NB) bsum[t] = buf[t];
}

__global__ __launch_bounds__(256) void scan_add_kernel(int* __restrict__ rowptr,
                                                       const int* __restrict__ bsum, int N) {
  int b = blockIdx.x, t = threadIdx.x, i = b * 256 + t;
  if (b > 0 && i < N) rowptr[i + 1] += bsum[b - 1];
}

__global__ __launch_bounds__(256) void fill_kernel(const int* __restrict__ ei,
                                                   const int* __restrict__ flag,
                                                   int E, int N,
                                                   const int* __restrict__ rowptr,
                                                   int* __restrict__ fillc,
                                                   int* __restrict__ colbuf) {
  int e = blockIdx.x * 256 + threadIdx.x;
  if (e >= E + N) return;
  int s, d;
  if (e < E) { int is32 = *flag; s = load_src(ei, is32, E, e); d = load_dst(ei, is32, E, e); }
  else { s = e - E; d = s; }
  int pos = atomicAdd(&fillc[d], 1);
  colbuf[rowptr[d] + pos] = s;
}

// ---------------------------------------------------------------------------
// prep kernels
// ---------------------------------------------------------------------------
// fp32 -> interleaved packed (hi|lo<<16) uint per element
__global__ __launch_bounds__(256) void split_x_i_kernel(const float* __restrict__ h,
                                                        uint_t* __restrict__ hi,
                                                        int n) {
  int i = (blockIdx.x * 256 + threadIdx.x) * 4;
  if (i >= n) return;
  f32x4v v = *(const f32x4v*)&h[i];
  uint4 o;
  o.x = pack_hl(v[0]); o.y = pack_hl(v[1]); o.z = pack_hl(v[2]); o.w = pack_hl(v[3]);
  *(uint4*)&hi[i] = o;
}

// Wp [K=128][128] fp32 -> Bt hi/lo [128][128] row layout (for LDS-path GEMM)
__global__ __launch_bounds__(256) void split_wt_kernel(const float* __restrict__ W,
                                                       ushort_t* __restrict__ hi,
                                                       ushort_t* __restrict__ lo,
                                                       int Nn) {
  int t = blockIdx.x * 256 + threadIdx.x;
  if (t >= 128 * Nn) return;
  int n = t >> 7, k = t & 127;
  float f = W[(size_t)k * Nn + n];
  ushort_t hb = f_to_bf16(f);
  hi[t] = hb;
  lo[t] = f_to_bf16(f - bf16_to_f(hb));
}

// W [128][512] -> Wstack in MFMA-fragment layout (K=512):
// elem (col,k): off = ((col>>4)*64 + (k>>3))*128 + (col&15)*8 + (k&7)
// value = 0.25 * W[f][h*128+col] with k = h*128+f
__global__ __launch_bounds__(256) void split_wstack_frag_kernel(const float* __restrict__ W,
                                                                ushort_t* __restrict__ hi,
                                                                ushort_t* __restrict__ lo) {
  int t = blockIdx.x * 256 + threadIdx.x;   // 65536 = 128*512
  int c16 = t >> 13;
  int r = t & 8191;
  int k8 = r >> 7;
  int rem = r & 127;
  int rl = rem >> 3, kl = rem & 7;
  int col = c16 * 16 + rl;
  int k = k8 * 8 + kl;
  int h = k >> 7, f = k & 127;
  float v = 0.25f * W[(size_t)f * 512 + h * 128 + col];
  ushort_t hb = f_to_bf16(v);
  hi[t] = hb;
  lo[t] = f_to_bf16(v - bf16_to_f(hb));
}

// Ws[f*4+h] = sum_d W[f, h*128+d] * a_src[h, d]
// wave per f (f in [0,128)); 16-lane group per head.
__global__ __launch_bounds__(256) void wsd_kernel(const float* __restrict__ W,
                                                  const float* __restrict__ a_src,
                                                  const float* __restrict__ a_dst,
                                                  float* __restrict__ Ws,
                                                  float* __restrict__ Wd) {
  int wave = threadIdx.x >> 6, lane = threadIdx.x & 63;
  int f = blockIdx.x * 4 + wave;          // grid = 32 blocks -> f in [0,128)
  int base = lane * 8;
  float4 w0 = *(const float4*)&W[(size_t)f * 512 + base];
  float4 w1 = *(const float4*)&W[(size_t)f * 512 + base + 4];
  float4 s0 = *(const float4*)&a_src[base];
  float4 s1 = *(const float4*)&a_src[base + 4];
  float4 d0 = *(const float4*)&a_dst[base];
  float4 d1 = *(const float4*)&a_dst[base + 4];
  float ps = w0.x*s0.x + w0.y*s0.y + w0.z*s0.z + w0.w*s0.w
           + w1.x*s1.x + w1.y*s1.y + w1.z*s1.z + w1.w*s1.w;
  float pd = w0.x*d0.x + w0.y*d0.y + w0.z*d0.z + w0.w*d0.w
           + w1.x*d1.x + w1.y*d1.y + w1.z*d1.z + w1.w*d1.w;
#pragma unroll
  for (int off = 1; off <= 8; off <<= 1) {
    ps += __shfl_xor(ps, off);
    pd += __shfl_xor(pd, off);
  }
  if ((lane & 15) == 0) {
    int h = lane >> 4;
    Ws[f * 4 + h] = ps;
    Wd[f * 4 + h] = pd;
  }
}

// al_src/al_dst [N,4] from interleaved h. One wave per node.
__global__ __launch_bounds__(256) void al_kernel_i(const uint_t* __restrict__ hint,
                                                   const float* __restrict__ Ws,
                                                   const float* __restrict__ Wd,
                                                   float* __restrict__ al_src,
                                                   float* __restrict__ al_dst, int N) {
  __shared__ float sWs[512], sWd[512];
  int t = threadIdx.x;
  sWs[t] = Ws[t]; sWs[t + 256] = Ws[t + 256];
  sWd[t] = Wd[t]; sWd[t + 256] = Wd[t + 256];
  __syncthreads();
  int wave = t >> 6, lane = t & 63;
  int n = blockIdx.x * 4 + wave;
  if (n >= N) return;
  uint2 uu = *(const uint2*)&hint[(size_t)n * 128 + lane * 2];
  float v0 = lo16f(uu.x) + hi16f(uu.x);
  float v1 = lo16f(uu.y) + hi16f(uu.y);
  float p[8];
#pragma unroll
  for (int hh = 0; hh < 4; ++hh) {
    p[hh]     = v0 * sWs[(2 * lane) * 4 + hh] + v1 * sWs[(2 * lane + 1) * 4 + hh];
    p[4 + hh] = v0 * sWd[(2 * lane) * 4 + hh] + v1 * sWd[(2 * lane + 1) * 4 + hh];
  }
#pragma unroll
  for (int off = 32; off; off >>= 1)
#pragma unroll
    for (int i = 0; i < 8; ++i) p[i] += __shfl_xor(p[i], off);
  if (lane == 0) {
#pragma unroll
    for (int hh = 0; hh < 4; ++hh) {
      al_src[n * 4 + hh] = p[hh];
      al_dst[n * 4 + hh] = p[4 + hh];
    }
  }
}

// ---------------------------------------------------------------------------
// aggregation: G[n, head*128+f] = softmax-weighted sum of h[s,f]
// 2 nodes per wave, online softmax. OUTPUT IN MFMA-FRAGMENT LAYOUT.
// ---------------------------------------------------------------------------
__global__ __launch_bounds__(512) void agg_G_kernel(const uint_t* __restrict__ hint,
                                                    const float* __restrict__ al_src,
                                                    const float* __restrict__ al_dst,
                                                    const int* __restrict__ rowptr,
                                                    const int* __restrict__ colbuf,
                                                    ushort_t* __restrict__ Ghi,
                                                    ushort_t* __restrict__ Glo, int N) {
  int wave = threadIdx.x >> 6, lane = threadIdx.x & 63;
  int fl = lane & 31;
  int n = blockIdx.x * 16 + wave * 2 + (lane >> 5);
  bool alive = n < N;
  int beg = 0, d = 0;
  float4 ald = make_float4(0.f, 0.f, 0.f, 0.f);
  if (alive) {
    beg = rowptr[n];
    d = rowptr[n + 1] - beg;
    ald = *(const float4*)&al_dst[(size_t)n * 4];
  }
  int dmax = max(d, __shfl_xor(d, 32));
  float m[4], ss[4], acc[4][4];
#pragma unroll
  for (int h = 0; h < 4; ++h) {
    m[h] = -1e30f; ss[h] = 0.f;
#pragma unroll
    for (int k = 0; k < 4; ++k) acc[h][k] = 0.f;
  }
  for (int it = 0; it < dmax; ++it) {
    bool valid = it < d;
    int s = colbuf[valid ? beg + it : beg];
    float4 as = *(const float4*)&al_src[(size_t)s * 4];
    uint4 hv = *(const uint4*)&hint[(size_t)s * 128 + fl * 4];
    float e[4];
    e[0] = as.x + ald.x; e[1] = as.y + ald.y; e[2] = as.z + ald.z; e[3] = as.w + ald.w;
#pragma unroll
    for (int h = 0; h < 4; ++h) {
      e[h] = e[h] > 0.f ? e[h] : 0.2f * e[h];
      e[h] = valid ? e[h] : -1e30f;
    }
    if (__any(e[0] > m[0] || e[1] > m[1] || e[2] > m[2] || e[3] > m[3])) {
#pragma unroll
      for (int h = 0; h < 4; ++h) {
        float nm = fmaxf(m[h], e[h]);
        float f = __expf(m[h] - nm);
        m[h] = nm;
        ss[h] *= f;
#pragma unroll
        for (int k = 0; k < 4; ++k) acc[h][k] *= f;
      }
    }
    float v[4];
    v[0] = lo16f(hv.x) + hi16f(hv.x);
    v[1] = lo16f(hv.y) + hi16f(hv.y);
    v[2] = lo16f(hv.z) + hi16f(hv.z);
    v[3] = lo16f(hv.w) + hi16f(hv.w);
#pragma unroll
    for (int h = 0; h < 4; ++h) {
      float w = __expf(e[h] - m[h]);
      ss[h] += w;
#pragma unroll
      for (int k = 0; k < 4; ++k) acc[h][k] += w * v[k];
    }
  }
  if (!alive) return;
#pragma unroll
  for (int h = 0; h < 4; ++h) {
    float inv = 1.f / (ss[h] + 1e-16f);
    float g0 = acc[h][0] * inv, g1 = acc[h][1] * inv;
    float g2 = acc[h][2] * inv, g3 = acc[h][3] * inv;
    ushort_t h0 = f_to_bf16(g0), h1 = f_to_bf16(g1), h2 = f_to_bf16(g2), h3 = f_to_bf16(g3);
    ushort_t l0 = f_to_bf16(g0 - bf16_to_f(h0)), l1 = f_to_bf16(g1 - bf16_to_f(h1));
    ushort_t l2 = f_to_bf16(g2 - bf16_to_f(h2)), l3 = f_to_bf16(g3 - bf16_to_f(h3));
    // fragment layout: c = h*128 + fl*4  ->  k8 = h*16 + (fl>>1), kl = (fl&1)*4
    size_t o = ((size_t)(n >> 4) * 64 + h * 16 + (fl >> 1)) * 128 + (n & 15) * 8 + (fl & 1) * 4;
    *(uint2*)&Ghi[o] = make_uint2((uint_t)h0 | ((uint_t)h1 << 16),
                                  (uint_t)h2 | ((uint_t)h3 << 16));
    *(uint2*)&Glo[o] = make_uint2((uint_t)l0 | ((uint_t)l1 << 16),
                                  (uint_t)l2 | ((uint_t)l3 << 16));
  }
}

// ---------------------------------------------------------------------------
// Barrier-free MFMA GEMM from fragment-layout inputs (K=512, 128 out cols).
// 1 wave per block; wave owns 32 rows x 128 cols; acc 2x8 frags.
// ---------------------------------------------------------------------------
__global__ __launch_bounds__(64) void mfma_gemm_frag_kernel(
    const ushort_t* __restrict__ Ahi, const ushort_t* __restrict__ Alo,
    const ushort_t* __restrict__ Bhi, const ushort_t* __restrict__ Blo,
    uint_t* __restrict__ Ci, ushort_t* __restrict__ Chi, ushort_t* __restrict__ Clo,
    int M, const float* __restrict__ bias) {
  int lane = threadIdx.x;
  int wid = blockIdx.x;
  int krow = lane >> 4, ml = lane & 15;
  int lb = krow * 128 + ml * 8;          // lane offset within a fragment block
  size_t abase = (size_t)wid * 16384 + lb;
  f32x4 acc[2][8] = {};
#pragma unroll 2
  for (int kt = 0; kt < 16; ++kt) {
    short8 ah0 = *(const short8*)&Ahi[abase + kt * 512];
    short8 ah1 = *(const short8*)&Ahi[abase + 8192 + kt * 512];
    short8 al0 = *(const short8*)&Alo[abase + kt * 512];
    short8 al1 = *(const short8*)&Alo[abase + 8192 + kt * 512];
#pragma unroll
    for (int j = 0; j < 8; ++j) {
      short8 bh = *(const short8*)&Bhi[j * 8192 + kt * 512 + lb];
      short8 bl = *(const short8*)&Blo[j * 8192 + kt * 512 + lb];
      acc[0][j] = __builtin_amdgcn_mfma_f32_16x16x32_bf16(ah0, bh, acc[0][j], 0, 0, 0);
      acc[0][j] = __builtin_amdgcn_mfma_f32_16x16x32_bf16(ah0, bl, acc[0][j], 0, 0, 0);
      acc[0][j] = __builtin_amdgcn_mfma_f32_16x16x32_bf16(al0, bh, acc[0][j], 0, 0, 0);
      acc[1][j] = __builtin_amdgcn_mfma_f32_16x16x32_bf16(ah1, bh, acc[1][j], 0, 0, 0);
      acc[1][j] = __builtin_amdgcn_mfma_f32_16x16x32_bf16(ah1, bl, acc[1][j], 0, 0, 0);
      acc[1][j] = __builtin_amdgcn_mfma_f32_16x16x32_bf16(al1, bh, acc[1][j], 0, 0, 0);
    }
  }
  int wrow0 = wid * 32;
#pragma unroll
  for (int j = 0; j < 8; ++j) {
    int col = j * 16 + ml;
    float bv = bias[col];
#pragma unroll
    for (int i = 0; i < 2; ++i) {
#pragma unroll
      for (int r = 0; r < 4; ++r) {
        int row = wrow0 + i * 16 + krow * 4 + r;
        if (row < M) {
          float v = fmaxf(acc[i][j][r] + bv, 0.f);   // relu fused
          if (Ci) {
            Ci[(size_t)row * 128 + col] = pack_hl(v);
          } else {
            ushort_t hb = f_to_bf16(v);
            Chi[(size_t)row * 128 + col] = hb;
            Clo[(size_t)row * 128 + col] = f_to_bf16(v - bf16_to_f(hb));
          }
        }
      }
    }
  }
}

// ---------------------------------------------------------------------------
// LDS-staged MFMA GEMM (kept for the final projection, K=128, fp32 out)
// ---------------------------------------------------------------------------
__global__ __launch_bounds__(256) void mfma_gemm_kernel(
    const ushort_t* __restrict__ Ahi, const ushort_t* __restrict__ Alo,
    const ushort_t* __restrict__ Bthi, const ushort_t* __restrict__ Btlo,
    int K, float* __restrict__ Cf, int M, const float* __restrict__ bias) {
  __shared__ ushort_t As[2][128 * 128];  // 64 KB
  int tid = threadIdx.x;
  int wave = tid >> 6, lane = tid & 63;
  int wr = wave >> 1, wc = wave & 1;
  int row0 = blockIdx.x * 128;
  int krow = lane >> 4, ml = lane & 15;
  f32x4 acc[4][4] = {};

  for (int ko = 0; ko < K; ko += 128) {
#pragma unroll
    for (int p = 0; p < 2; ++p) {
      const ushort_t* src = p ? Alo : Ahi;
#pragma unroll
      for (int it = 0; it < 8; ++it) {
        int chunk = wave + it * 4;
        int row = chunk * 4 + (lane >> 4);
        int sp = lane & 15;
        int sl = sp ^ (row & 7);
        gload_lds16(src + (size_t)(row0 + row) * K + ko + sl * 8,
                    &As[p][chunk * 512]);
      }
    }
    __syncthreads();
#pragma unroll
    for (int kt = 0; kt < 4; ++kt) {
      short8 ah[4], al_[4], bh[4], bl[4];
      int sl = kt * 4 + krow;
#pragma unroll
      for (int f = 0; f < 4; ++f) {
        int row = wr * 64 + f * 16 + ml;
        int phys = sl ^ (row & 7);
        int off = row * 128 + phys * 8;
        ah[f]  = *(const short8*)&As[0][off];
        al_[f] = *(const short8*)&As[1][off];
      }
      int k0 = ko + kt * 32 + krow * 8;
#pragma unroll
      for (int f = 0; f < 4; ++f) {
        int nn = wc * 64 + f * 16 + ml;
        bh[f] = *(const short8*)&Bthi[(size_t)nn * K + k0];
        bl[f] = *(const short8*)&Btlo[(size_t)nn * K + k0];
      }
#pragma unroll
      for (int i = 0; i < 4; ++i)
#pragma unroll
        for (int j = 0; j < 4; ++j) {
          acc[i][j] = __builtin_amdgcn_mfma_f32_16x16x32_bf16(ah[i],  bh[j], acc[i][j], 0, 0, 0);
          acc[i][j] = __builtin_amdgcn_mfma_f32_16x16x32_bf16(ah[i],  bl[j], acc[i][j], 0, 0, 0);
          acc[i][j] = __builtin_amdgcn_mfma_f32_16x16x32_bf16(al_[i], bh[j], acc[i][j], 0, 0, 0);
        }
    }
    __syncthreads();
  }

#pragma unroll
  for (int j = 0; j < 4; ++j) {
    int col = wc * 64 + j * 16 + ml;
    float bv = bias[col];
#pragma unroll
    for (int i = 0; i < 4; ++i) {
#pragma unroll
      for (int r = 0; r < 4; ++r) {
        int row = row0 + wr * 64 + i * 16 + krow * 4 + r;
        if (row < M) Cf[(size_t)row * 128 + col] = acc[i][j][r] + bv;
      }
    }
  }
}

// ---------------------------------------------------------------------------
extern "C" void kernel_launch(void* const* d_in, const int* in_sizes, int n_in,
                              void* d_out, int out_size, void* d_ws, size_t ws_size,
                              hipStream_t stream) {
  const float* x  = (const float*)d_in[0];
  const int*   ei = (const int*)d_in[1];
  const float* Wl[3]  = {(const float*)d_in[2], (const float*)d_in[6], (const float*)d_in[10]};
  const float* asr[3] = {(const float*)d_in[3], (const float*)d_in[7], (const float*)d_in[11]};
  const float* adr[3] = {(const float*)d_in[4], (const float*)d_in[8], (const float*)d_in[12]};
  const float* bl[3]  = {(const float*)d_in[5], (const float*)d_in[9], (const float*)d_in[13]};
  const float* Wp = (const float*)d_in[14];
  const float* bp = (const float*)d_in[15];

  const int N = in_sizes[0] / 128;   // 50000
  const int E = in_sizes[1] / 2;     // 400000
  const int EN = E + N;
  const int Mtiles = (N + 127) / 128;  // 391
  const int Mp = Mtiles * 128;         // 50048
  const int NB = (N + 255) / 256;      // scan blocks
  const int NW = Mp / 32;              // 1564 GEMM waves

  char* ws = (char*)d_ws;
  size_t off = 0;
  auto carve = [&](size_t bytes) -> void* {
    void* p = ws + off;
    off = (off + bytes + 255) & ~(size_t)255;
    return p;
  };
  ushort_t* Ghi   = (ushort_t*)carve((size_t)Mp * 512 * 2);  // frag layout, 51.2 MB
  ushort_t* Glo   = (ushort_t*)carve((size_t)Mp * 512 * 2);
  uint_t*   hiA   = (uint_t*)carve((size_t)N * 128 * 4);     // interleaved row layout
  uint_t*   hiB   = (uint_t*)carve((size_t)N * 128 * 4);
  ushort_t* h3hi  = (ushort_t*)carve((size_t)Mp * 128 * 2);  // row layout (proj input)
  ushort_t* h3lo  = (ushort_t*)carve((size_t)Mp * 128 * 2);
  ushort_t* wshi  = (ushort_t*)carve((size_t)128 * 512 * 2); // frag layout Wstack
  ushort_t* wslo  = (ushort_t*)carve((size_t)128 * 512 * 2);
  float*    alsrc = (float*)carve((size_t)N * 4 * 4);
  float*    aldst = (float*)carve((size_t)N * 4 * 4);
  float*    Wsb   = (float*)carve(512 * 4);
  float*    Wdb   = (float*)carve(512 * 4);
  int*      rowptr= (int*)carve((size_t)(N + 1) * 4);
  int*      deg   = (int*)carve((size_t)N * 4);
  int*      bsum  = (int*)carve(256 * 4);
  int*      fillc = (int*)carve((size_t)N * 4);
  int*      colbuf= (int*)carve((size_t)EN * 4);
  int*      flag  = (int*)carve(256);

  // ---- CSR build ----
  detect_i64_kernel<<<1, 64, 0, stream>>>(ei, flag);
  hipMemsetAsync(deg, 0, (size_t)N * 4, stream);
  hipMemsetAsync(fillc, 0, (size_t)N * 4, stream);
  int ebl = (EN + 255) / 256;
  deg_kernel<<<ebl, 256, 0, stream>>>(ei, flag, E, N, deg);
  scan_blk_kernel<<<NB, 256, 0, stream>>>(deg, rowptr, bsum, N);
  scan_top_kernel<<<1, 256, 0, stream>>>(bsum, NB);
  scan_add_kernel<<<NB, 256, 0, stream>>>(rowptr, bsum, N);
  fill_kernel<<<ebl, 256, 0, stream>>>(ei, flag, E, N, rowptr, fillc, colbuf);

  // ---- split x into interleaved packed bf16 hi/lo ----
  const int n_real = N * 128;
  split_x_i_kernel<<<(n_real / 4 + 255) / 256, 256, 0, stream>>>(x, hiA, n_real);

  // ---- 3 GAT layers ----
  uint_t* hin = hiA;
  uint_t* hnext = hiB;
  for (int L = 0; L < 3; ++L) {
    wsd_kernel<<<32, 256, 0, stream>>>(Wl[L], asr[L], adr[L], Wsb, Wdb);
    al_kernel_i<<<(N + 3) / 4, 256, 0, stream>>>(hin, Wsb, Wdb, alsrc, aldst, N);
    agg_G_kernel<<<(N + 15) / 16, 512, 0, stream>>>(hin, alsrc, aldst,
                                                    rowptr, colbuf, Ghi, Glo, N);
    split_wstack_frag_kernel<<<256, 256, 0, stream>>>(Wl[L], wshi, wslo);
    if (L < 2) {
      mfma_gemm_frag_kernel<<<NW, 64, 0, stream>>>(Ghi, Glo, wshi, wslo,
                                                   hnext, nullptr, nullptr, N, bl[L]);
      uint_t* t = hin; hin = hnext; hnext = t;
    } else {
      mfma_gemm_frag_kernel<<<NW, 64, 0, stream>>>(Ghi, Glo, wshi, wslo,
                                                   nullptr, h3hi, h3lo, N, bl[L]);
    }
  }

  // ---- final projection: out = h3 @ Wp + bp (fp32 out) ----
  split_wt_kernel<<<(128 * 128) / 256, 256, 0, stream>>>(Wp, wshi, wslo, 128);
  mfma_gemm_kernel<<<Mtiles, 256, 0, stream>>>(h3hi, h3lo, wshi, wslo, 128,
                                               (float*)d_out, N, bp);
}